// Round 6
// baseline (713.639 us; speedup 1.0000x reference)
//
#include <hip/hip_runtime.h>
#include <stdint.h>

#define BS_T   16384
#define XDIM   4096
#define KDIM   512
#define NKEYS  4096
#define KTOP   16

typedef _Float16 half8  __attribute__((ext_vector_type(8)));
typedef float    floatx4 __attribute__((ext_vector_type(4)));

// async global->LDS, 16B per lane; LDS dest is wave-uniform base + lane*16
__device__ static inline void gload_lds16(const void* g, void* l) {
  __builtin_amdgcn_global_load_lds(
      (const __attribute__((address_space(1))) uint32_t*)(uintptr_t)g,
      (__attribute__((address_space(3))) uint32_t*)(uint32_t)(uintptr_t)l,
      16, 0, 0);
}

// ---------------- fp32 -> fp16 convert (vectorized, grid-stride) ----------------
__global__ __launch_bounds__(256) void cvt_f32_f16_v(const float* __restrict__ in,
                                                     _Float16* __restrict__ out, int n8) {
  int stride = gridDim.x * 256;
  for (int i = blockIdx.x * 256 + threadIdx.x; i < n8; i += stride) {
    float4 v0 = ((const float4*)in)[2 * i];
    float4 v1 = ((const float4*)in)[2 * i + 1];
    half8 h = { (_Float16)v0.x, (_Float16)v0.y, (_Float16)v0.z, (_Float16)v0.w,
                (_Float16)v1.x, (_Float16)v1.y, (_Float16)v1.z, (_Float16)v1.w };
    ((half8*)out)[i] = h;
  }
}

// ---------------- GEMM1 fused v2: Q[M,512] = cvt16(X[M,4096]) @ W16^T + b ----------
// BM=64, BN=512 (full N): X panel read exactly once from HBM. A goes global->VGPR
// directly in MFMA fragment layout (all 8 waves read the same 64x64 fp32 tile ->
// L1-served after wave 0), cvt to fp16 in-register. B (W16, L2-resident) staged via
// double-buffered gload_lds. LDS traffic halved vs v1; no ds_write/lgkm chain on A.
__global__ __launch_bounds__(512, 2)
void gemm1_fused(const float* __restrict__ X, const _Float16* __restrict__ Wh,
                 const float* __restrict__ bias, _Float16* __restrict__ Q) {
  __shared__ __align__(16) _Float16 ldsB[2][512 * 64];   // 128 KB

  const int tid  = threadIdx.x;
  const int lane = tid & 63;
  const int wid  = tid >> 6;            // 0..7
  const int rowBase = blockIdx.x * 64;
  const int wc  = wid * 64;             // wave's 64-col slice of N
  const int l15 = lane & 15;
  const int q4  = lane >> 4;
  const int sub   = lane >> 3;
  const int gslot = (lane & 7) ^ sub;   // pre-swizzled global slot for gload_lds

  // A fragment base: lane reads rows m*16+l15, 8 consecutive floats at ks*32+q4*8
  const float* aBase = X + (size_t)rowBase * XDIM;
  const size_t aRowOff[4] = { (size_t)(0 * 16 + l15) * XDIM, (size_t)(1 * 16 + l15) * XDIM,
                              (size_t)(2 * 16 + l15) * XDIM, (size_t)(3 * 16 + l15) * XDIM };

  floatx4 acc[4][4];
  #pragma unroll
  for (int m = 0; m < 4; ++m)
    #pragma unroll
    for (int n = 0; n < 4; ++n)
      acc[m][n] = (floatx4)0.0f;

  auto stageB = [&](int kt, int buf) {
    #pragma unroll
    for (int i = 0; i < 8; ++i) {
      int g = wid * 8 + i;              // 64 groups of 8 rows x 128B
      gload_lds16(Wh + (size_t)(g * 8 + sub) * XDIM + kt + gslot * 8,
                  (char*)&ldsB[buf][0] + g * 1024);
    }
  };
  auto loadA = [&](int kt, float4* f) {
    #pragma unroll
    for (int m = 0; m < 4; ++m)
      #pragma unroll
      for (int ks = 0; ks < 2; ++ks)
        #pragma unroll
        for (int j = 0; j < 2; ++j)
          f[(m * 2 + ks) * 2 + j] =
              *(const float4*)(aBase + aRowOff[m] + kt + ks * 32 + q4 * 8 + j * 4);
  };

  // prologue
  float4 fA[16];
  loadA(0, fA);
  stageB(0, 0);
  __syncthreads();

  int cur = 0;
  #pragma unroll 2
  for (int t = 0; t < 64; ++t) {
    float4 fN[16];
    if (t < 63) {
      loadA((t + 1) * 64, fN);          // A(t+1): global->reg, L1-shared across waves
      stageB((t + 1) * 64, cur ^ 1);    // B(t+1): async -> other LDS buf
    }
    // compute(t): cvt A regs -> fp16 frags, ds_read B, 32 MFMA
    const char* bB = (const char*)&ldsB[cur][0];
    #pragma unroll
    for (int ks = 0; ks < 2; ++ks) {
      const int s = ks * 4 + q4;
      half8 b[4];
      #pragma unroll
      for (int n = 0; n < 4; ++n) {
        int row = wc + n * 16 + l15;
        b[n] = *(const half8*)(bB + row * 128 + ((s * 16) ^ ((row & 7) << 4)));
      }
      #pragma unroll
      for (int m = 0; m < 4; ++m) {
        float4 v0 = fA[(m * 2 + ks) * 2 + 0];
        float4 v1 = fA[(m * 2 + ks) * 2 + 1];
        half8 a = { (_Float16)v0.x, (_Float16)v0.y, (_Float16)v0.z, (_Float16)v0.w,
                    (_Float16)v1.x, (_Float16)v1.y, (_Float16)v1.z, (_Float16)v1.w };
        #pragma unroll
        for (int n = 0; n < 4; ++n)
          acc[m][n] = __builtin_amdgcn_mfma_f32_16x16x32_f16(a, b[n], acc[m][n], 0, 0, 0);
      }
    }
    __syncthreads();                    // drains B(t+1) gload_lds; next step reads buf^1
    #pragma unroll
    for (int i = 0; i < 16; ++i) fA[i] = fN[i];
    cur ^= 1;
  }

  // epilogue: C/D layout col=lane&15, row=(lane>>4)*4+r; fused bias + fp16 store
  #pragma unroll
  for (int m = 0; m < 4; ++m) {
    #pragma unroll
    for (int n = 0; n < 4; ++n) {
      int col = wc + n * 16 + l15;
      float bv = bias[col];
      #pragma unroll
      for (int r = 0; r < 4; ++r) {
        int row = rowBase + m * 16 + q4 * 4 + r;
        Q[(size_t)row * KDIM + col] = (_Float16)(acc[m][n][r] + bv);
      }
    }
  }
}

// ---------------- NT GEMM2: C[M,N] = A[M,K] * B[N,K]^T, fp16 in, fp32 out ----------
template<int BM, int BN, int WAVES, int WGN, int MINW>
__global__ __launch_bounds__(WAVES * 64, MINW)
void gemm16(const _Float16* __restrict__ A, const _Float16* __restrict__ B,
            float* __restrict__ outp, int M, int N, int K, int nCol) {
  __shared__ __align__(16) _Float16 ldsA[BM * 64];
  __shared__ __align__(16) _Float16 ldsB[BN * 64];

  const int tid = threadIdx.x;
  const int cpx = gridDim.x >> 3;
  const int bid = (blockIdx.x & 7) * cpx + (blockIdx.x >> 3);
  const int rowBase = (bid / nCol) * BM;
  const int colBase = (bid % nCol) * BN;
  const int lane = tid & 63;
  const int wid  = tid >> 6;
  const int wr = (wid / WGN) * 64;
  const int wc = (wid % WGN) * 64;
  const int l15 = lane & 15;
  const int q4  = lane >> 4;

  const int sub   = lane >> 3;
  const int gslot = (lane & 7) ^ sub;

  constexpr int GROUPS = (BM + BN) / 8;
  constexpr int GPW    = GROUPS / WAVES;

  floatx4 acc[4][4];
  #pragma unroll
  for (int m = 0; m < 4; ++m)
    #pragma unroll
    for (int n = 0; n < 4; ++n)
      acc[m][n] = (floatx4)0.0f;

  for (int kt = 0; kt < K; kt += 64) {
    #pragma unroll
    for (int i = 0; i < GPW; ++i) {
      int g = wid * GPW + i;
      if (g < BM / 8) {
        const _Float16* src = A + (size_t)(rowBase + g * 8 + sub) * K + kt + gslot * 8;
        gload_lds16(src, (char*)ldsA + g * 1024);
      } else {
        int gb = g - BM / 8;
        const _Float16* src = B + (size_t)(colBase + gb * 8 + sub) * K + kt + gslot * 8;
        gload_lds16(src, (char*)ldsB + gb * 1024);
      }
    }
    __syncthreads();

    #pragma unroll
    for (int ks = 0; ks < 2; ++ks) {
      const int s = ks * 4 + q4;
      half8 a[4], b[4];
      #pragma unroll
      for (int m = 0; m < 4; ++m) {
        int row = wr + m * 16 + l15;
        a[m] = *(const half8*)((const char*)ldsA + row * 128 + ((s * 16) ^ ((row & 7) << 4)));
      }
      #pragma unroll
      for (int n = 0; n < 4; ++n) {
        int row = wc + n * 16 + l15;
        b[n] = *(const half8*)((const char*)ldsB + row * 128 + ((s * 16) ^ ((row & 7) << 4)));
      }
      #pragma unroll
      for (int m = 0; m < 4; ++m)
        #pragma unroll
        for (int n = 0; n < 4; ++n)
          acc[m][n] = __builtin_amdgcn_mfma_f32_16x16x32_f16(a[m], b[n], acc[m][n], 0, 0, 0);
    }
    __syncthreads();
  }

  #pragma unroll
  for (int m = 0; m < 4; ++m) {
    #pragma unroll
    for (int n = 0; n < 4; ++n) {
      int col = colBase + wc + n * 16 + l15;
      #pragma unroll
      for (int r = 0; r < 4; ++r) {
        int row = rowBase + wr + m * 16 + q4 * 4 + r;
        outp[(size_t)row * N + col] = acc[m][n][r];
      }
    }
  }
}

// ---------------- top-16 + scatter-softmax gates (radix-select) ----------------
__global__ __launch_bounds__(256) void topk_gates_kernel(const float* __restrict__ scores,
                                                         float* __restrict__ gates) {
  __shared__ uint32_t hist[4096];            // 16KB; reused as candidate store
  __shared__ uint32_t sA[256];
  __shared__ uint32_t av[16], ai[16];
  __shared__ uint32_t sk[KTOP], si[KTOP];
  __shared__ uint32_t cntA, cntC;
  __shared__ int s_p; __shared__ uint32_t s_above;
  __shared__ float gk[KTOP]; __shared__ float s_gother;

  const int tid  = threadIdx.x;
  const int lane = tid & 63;
  const int w    = tid >> 6;
  const float* srow = scores + (size_t)blockIdx.x * NKEYS;

  uint4 z4 = {0, 0, 0, 0};
  #pragma unroll
  for (int i = 0; i < 4; ++i) ((uint4*)hist)[tid + 256 * i] = z4;
  if (tid == 0) { cntA = 0; cntC = 0; }

  uint32_t key[16];
  const int base = (w << 10) + (lane << 4);
  {
    const float4* p4 = (const float4*)(srow + base);
    #pragma unroll
    for (int i = 0; i < 4; ++i) {
      float4 t = p4[i];
      float tv[4] = { t.x, t.y, t.z, t.w };
      #pragma unroll
      for (int c = 0; c < 4; ++c) {
        uint32_t u = __float_as_uint(tv[c]);
        key[i * 4 + c] = u ^ (uint32_t)(((int32_t)u >> 31) | 0x80000000);
      }
    }
  }
  __syncthreads();

  #pragma unroll
  for (int j = 0; j < 16; ++j) atomicAdd(&hist[key[j] >> 20], 1u);
  __syncthreads();

  uint32_t h[16];
  #pragma unroll
  for (int i = 0; i < 16; ++i) h[i] = hist[tid * 16 + i];
  uint32_t sfx[17]; sfx[16] = 0;
  #pragma unroll
  for (int i = 15; i >= 0; --i) sfx[i] = sfx[i + 1] + h[i];
  sA[tid] = sfx[0];
  __syncthreads();
  uint32_t s = sfx[0];
  #pragma unroll
  for (int off = 1; off < 256; off <<= 1) {
    uint32_t add = (tid + off < 256) ? sA[tid + off] : 0;
    __syncthreads();
    s += add; sA[tid] = s;
    __syncthreads();
  }
  const uint32_t exclHi = s - sfx[0];

  #pragma unroll
  for (int i = 0; i < 16; ++i) {
    uint32_t cg = exclHi + sfx[i + 1];
    if (cg < KTOP && cg + h[i] >= KTOP) { s_p = tid * 16 + i; s_above = cg; }
  }
  __syncthreads();
  const uint32_t p = (uint32_t)s_p;
  const uint32_t above = s_above;
  const uint32_t need = KTOP - above;

  uint32_t* ck = hist;
  uint32_t* ci = hist + 2048;
  #pragma unroll
  for (int j = 0; j < 16; ++j) {
    uint32_t b = key[j] >> 20;
    if (b >= p) {
      uint32_t idx = (uint32_t)(base + j);
      if (b > p) { uint32_t pos = atomicAdd(&cntA, 1u); av[pos] = key[j]; ai[pos] = idx; }
      else       { uint32_t pos = atomicAdd(&cntC, 1u); if (pos < 2048u) { ck[pos] = key[j]; ci[pos] = idx; } }
    }
  }
  __syncthreads();

  const uint32_t nA = cntA;
  if (tid < nA) { sk[tid] = av[tid]; si[tid] = ai[tid]; }

  if (w == 0) {
    const uint32_t nC = min(cntC, 2048u);
    for (uint32_t k = 0; k < need; ++k) {
      uint32_t bk = 0, bi = 0xFFFFFFFFu, bp = 0;
      for (uint32_t c = lane; c < nC; c += 64) {
        uint32_t kk = ck[c], ii = ci[c];
        if (kk > bk || (kk == bk && ii < bi)) { bk = kk; bi = ii; bp = c; }
      }
      #pragma unroll
      for (int off = 32; off >= 1; off >>= 1) {
        uint32_t ok = __shfl_down(bk, off);
        uint32_t oi = __shfl_down(bi, off);
        uint32_t op = __shfl_down(bp, off);
        if (ok > bk || (ok == bk && oi < bi)) { bk = ok; bi = oi; bp = op; }
      }
      bp = __shfl(bp, 0);
      if (lane == 0) { ck[bp] = 0; sk[nA + k] = bk; si[nA + k] = bi; }
    }
  }
  __syncthreads();

  if (tid == 0) {
    float f[KTOP]; float mx = 0.f;
    #pragma unroll
    for (int k = 0; k < KTOP; ++k) {
      uint32_t kk = sk[k];
      float fv = (kk & 0x80000000u) ? __uint_as_float(kk ^ 0x80000000u)
                                    : __uint_as_float(~kk);
      f[k] = fv; mx = fmaxf(mx, fv);
    }
    float eo = __expf(-mx);
    float Z = (float)(NKEYS - KTOP) * eo;
    float e[KTOP];
    #pragma unroll
    for (int k = 0; k < KTOP; ++k) { e[k] = __expf(f[k] - mx); Z += e[k]; }
    float inv = 1.f / Z;
    #pragma unroll
    for (int k = 0; k < KTOP; ++k) gk[k] = e[k] * inv;
    s_gother = eo * inv;
  }
  __syncthreads();

  float go = s_gother;
  float4 g4 = { go, go, go, go };
  float* grow = gates + (size_t)blockIdx.x * NKEYS;
  #pragma unroll
  for (int j = 0; j < 4; ++j) ((float4*)grow)[j * 256 + tid] = g4;
  __syncthreads();
  if (tid < KTOP) grow[si[tid]] = gk[tid];
}

extern "C" void kernel_launch(void* const* d_in, const int* in_sizes, int n_in,
                              void* d_out, int out_size, void* d_ws, size_t ws_size,
                              hipStream_t stream) {
  const float* x    = (const float*)d_in[0];
  const float* keys = (const float*)d_in[1];
  const float* W    = (const float*)d_in[2];
  const float* bias = (const float*)d_in[3];
  (void)in_sizes; (void)n_in; (void)out_size; (void)ws_size;

  float* gates  = (float*)d_out;
  float* scores = (float*)d_out + (size_t)BS_T * NKEYS;

  _Float16* W_h = (_Float16*)d_ws;                 // 4 MB
  _Float16* k_h = W_h + (size_t)KDIM * XDIM;       // 4 MB
  _Float16* q_h = k_h + (size_t)NKEYS * KDIM;      // 16 MB

  cvt_f32_f16_v<<<dim3(1024), dim3(256), 0, stream>>>(W, W_h, KDIM * XDIM / 8);
  cvt_f32_f16_v<<<dim3(1024), dim3(256), 0, stream>>>(keys, k_h, NKEYS * KDIM / 8);

  // query = x @ W^T + b -> q_h (fp16); x read ONCE (fp32), A direct-to-reg
  gemm1_fused<<<dim3(BS_T / 64), dim3(512), 0, stream>>>(x, W_h, bias, q_h);

  // scores = q @ keys^T -> fp32. 128x128 tiles, 4 waves (2x2), grid 4096
  gemm16<128, 128, 4, 2, 3><<<dim3((BS_T / 128) * (NKEYS / 128)), dim3(256), 0, stream>>>(
      q_h, k_h, scores, BS_T, NKEYS, KDIM, NKEYS / 128);

  topk_gates_kernel<<<dim3(BS_T), dim3(256), 0, stream>>>(scores, gates);
}

// Round 7
// 415.169 us; speedup vs baseline: 1.7189x; 1.7189x over previous
//
#include <hip/hip_runtime.h>
#include <stdint.h>

#define BS_T   16384
#define XDIM   4096
#define KDIM   512
#define NKEYS  4096
#define KTOP   16

typedef _Float16 half8  __attribute__((ext_vector_type(8)));
typedef float    floatx4 __attribute__((ext_vector_type(4)));

// async global->LDS, 16B per lane; LDS dest is wave-uniform base + lane*16
__device__ static inline void gload_lds16(const void* g, void* l) {
  __builtin_amdgcn_global_load_lds(
      (const __attribute__((address_space(1))) uint32_t*)(uintptr_t)g,
      (__attribute__((address_space(3))) uint32_t*)(uint32_t)(uintptr_t)l,
      16, 0, 0);
}

// ---------------- fp32 -> fp16 convert (vectorized, grid-stride) ----------------
__global__ __launch_bounds__(256) void cvt_f32_f16_v(const float* __restrict__ in,
                                                     _Float16* __restrict__ out, int n8) {
  int stride = gridDim.x * 256;
  for (int i = blockIdx.x * 256 + threadIdx.x; i < n8; i += stride) {
    float4 v0 = ((const float4*)in)[2 * i];
    float4 v1 = ((const float4*)in)[2 * i + 1];
    half8 h = { (_Float16)v0.x, (_Float16)v0.y, (_Float16)v0.z, (_Float16)v0.w,
                (_Float16)v1.x, (_Float16)v1.y, (_Float16)v1.z, (_Float16)v1.w };
    ((half8*)out)[i] = h;
  }
}

// ---------------- GEMM1 fused v3: Q[M,512] = cvt16(X[M,4096]) @ W16^T + b ----------
// BM=64, BN=512 (full N): X read once, coalesced (256B/row), cvt in-register during
// LDS staging. B staged via dbuf gload_lds. KEY: wave w's B cols == the LDS groups
// wave w stages itself -> B needs NO barrier, only own-wave counted vmcnt. The
// barrier only orders the 8KB A ds_writes (lgkmcnt). B(t+1) loads stay in flight
// across the barrier (T3/T4 counted-vmcnt; race-free by stage-own-slice).
__global__ __launch_bounds__(512, 2)
void gemm1_fused(const float* __restrict__ X, const _Float16* __restrict__ Wh,
                 const float* __restrict__ bias, _Float16* __restrict__ Q) {
  __shared__ __align__(16) _Float16 ldsA[2][64 * 64];    // 16 KB
  __shared__ __align__(16) _Float16 ldsB[2][512 * 64];   // 128 KB

  const int tid  = threadIdx.x;
  const int lane = tid & 63;
  const int wid  = tid >> 6;            // 0..7
  const int rowBase = blockIdx.x * 64;
  const int wc  = wid * 64;             // wave's 64-col slice of N
  const int l15 = lane & 15;
  const int q4  = lane >> 4;
  const int sub   = lane >> 3;
  const int gslot = (lane & 7) ^ sub;   // pre-swizzled global slot for gload_lds

  // A staging map: thread -> (row=tid>>3, 8-float slot=tid&7); coalesced 256B rows
  const int arow  = tid >> 3;
  const int aslot = tid & 7;
  const float* aSrc = X + (size_t)(rowBase + arow) * XDIM + aslot * 8;
  char* const aDst0 = (char*)&ldsA[0][0] + arow * 128 + ((aslot * 16) ^ ((arow & 7) << 4));
  char* const aDst1 = (char*)&ldsA[1][0] + arow * 128 + ((aslot * 16) ^ ((arow & 7) << 4));
  // B staging: wave w stages groups w*8..w*8+7 (rows wc..wc+63) == what it reads
  const _Float16* const bSrc = Wh + (size_t)(wc + sub) * XDIM + gslot * 8;
  char* const bDst0 = (char*)&ldsB[0][0] + wid * 8192;
  char* const bDst1 = (char*)&ldsB[1][0] + wid * 8192;

  floatx4 acc[4][4];
  #pragma unroll
  for (int m = 0; m < 4; ++m)
    #pragma unroll
    for (int n = 0; n < 4; ++n)
      acc[m][n] = (floatx4)0.0f;

  // ---- prologue: stage tile 0 into buf 0 ----
  {
    float4 v0 = *(const float4*)(aSrc);
    float4 v1 = *(const float4*)(aSrc + 4);
    __builtin_amdgcn_sched_barrier(0);          // A loads issue BEFORE B loads
    #pragma unroll
    for (int i = 0; i < 8; ++i)
      gload_lds16(bSrc + (size_t)i * 8 * XDIM, bDst0 + i * 1024);
    __builtin_amdgcn_sched_barrier(0);
    half8 h = { (_Float16)v0.x, (_Float16)v0.y, (_Float16)v0.z, (_Float16)v0.w,
                (_Float16)v1.x, (_Float16)v1.y, (_Float16)v1.z, (_Float16)v1.w };
    *(half8*)aDst0 = h;                          // auto-wait = vmcnt(8): B(0) in flight
    asm volatile("s_waitcnt lgkmcnt(0)" ::: "memory");
    __builtin_amdgcn_s_barrier();
  }

  for (int t = 0; t < 64; ++t) {
    const int pc = t & 1;
    const char* bA = pc ? (const char*)&ldsA[1][0] : (const char*)&ldsA[0][0];
    const char* bB = pc ? (const char*)&ldsB[1][0] : (const char*)&ldsB[0][0];
    char* adN = pc ? aDst0 : aDst1;
    char* bdN = pc ? bDst0 : bDst1;

    float4 n0, n1;
    if (t < 63) {
      const float* s0 = aSrc + (t + 1) * 64;
      n0 = *(const float4*)(s0);
      n1 = *(const float4*)(s0 + 4);
      __builtin_amdgcn_sched_barrier(0);        // keep A loads oldest
      const int ktn = (t + 1) * 64;
      #pragma unroll
      for (int i = 0; i < 8; ++i)
        gload_lds16(bSrc + (size_t)i * 8 * XDIM + ktn, bdN + i * 1024);
      __builtin_amdgcn_sched_barrier(0);
      asm volatile("s_waitcnt vmcnt(10)" ::: "memory");   // B(t) landed; 10 newest ok
    } else {
      asm volatile("s_waitcnt vmcnt(0)" ::: "memory");
    }

    // compute(t): ds_read A+B fragments, 32 MFMA
    #pragma unroll
    for (int ks = 0; ks < 2; ++ks) {
      const int s = ks * 4 + q4;
      half8 a[4], b[4];
      #pragma unroll
      for (int m = 0; m < 4; ++m) {
        int row = m * 16 + l15;
        a[m] = *(const half8*)(bA + row * 128 + ((s * 16) ^ ((row & 7) << 4)));
      }
      #pragma unroll
      for (int n = 0; n < 4; ++n) {
        int row = wc + n * 16 + l15;
        b[n] = *(const half8*)(bB + row * 128 + ((s * 16) ^ ((row & 7) << 4)));
      }
      #pragma unroll
      for (int m = 0; m < 4; ++m)
        #pragma unroll
        for (int n = 0; n < 4; ++n)
          acc[m][n] = __builtin_amdgcn_mfma_f32_16x16x32_f16(a[m], b[n], acc[m][n], 0, 0, 0);
    }

    if (t < 63) {
      half8 h = { (_Float16)n0.x, (_Float16)n0.y, (_Float16)n0.z, (_Float16)n0.w,
                  (_Float16)n1.x, (_Float16)n1.y, (_Float16)n1.z, (_Float16)n1.w };
      *(half8*)adN = h;                          // auto-wait vmcnt(8): A(t+1) only
    }
    asm volatile("s_waitcnt lgkmcnt(0)" ::: "memory");   // A writes visible
    __builtin_amdgcn_sched_barrier(0);
    __builtin_amdgcn_s_barrier();                // orders A only; B stays in flight
  }

  // epilogue: C/D layout col=lane&15, row=(lane>>4)*4+r; fused bias + fp16 store
  #pragma unroll
  for (int m = 0; m < 4; ++m) {
    #pragma unroll
    for (int n = 0; n < 4; ++n) {
      int col = wc + n * 16 + l15;
      float bv = bias[col];
      #pragma unroll
      for (int r = 0; r < 4; ++r) {
        int row = rowBase + m * 16 + q4 * 4 + r;
        Q[(size_t)row * KDIM + col] = (_Float16)(acc[m][n][r] + bv);
      }
    }
  }
}

// ---------------- NT GEMM2: C[M,N] = A[M,K] * B[N,K]^T, fp16 in, fp32 out ----------
template<int BM, int BN, int WAVES, int WGN, int MINW>
__global__ __launch_bounds__(WAVES * 64, MINW)
void gemm16(const _Float16* __restrict__ A, const _Float16* __restrict__ B,
            float* __restrict__ outp, int M, int N, int K, int nCol) {
  __shared__ __align__(16) _Float16 ldsA[BM * 64];
  __shared__ __align__(16) _Float16 ldsB[BN * 64];

  const int tid = threadIdx.x;
  const int cpx = gridDim.x >> 3;
  const int bid = (blockIdx.x & 7) * cpx + (blockIdx.x >> 3);
  const int rowBase = (bid / nCol) * BM;
  const int colBase = (bid % nCol) * BN;
  const int lane = tid & 63;
  const int wid  = tid >> 6;
  const int wr = (wid / WGN) * 64;
  const int wc = (wid % WGN) * 64;
  const int l15 = lane & 15;
  const int q4  = lane >> 4;

  const int sub   = lane >> 3;
  const int gslot = (lane & 7) ^ sub;

  constexpr int GROUPS = (BM + BN) / 8;
  constexpr int GPW    = GROUPS / WAVES;

  floatx4 acc[4][4];
  #pragma unroll
  for (int m = 0; m < 4; ++m)
    #pragma unroll
    for (int n = 0; n < 4; ++n)
      acc[m][n] = (floatx4)0.0f;

  for (int kt = 0; kt < K; kt += 64) {
    #pragma unroll
    for (int i = 0; i < GPW; ++i) {
      int g = wid * GPW + i;
      if (g < BM / 8) {
        const _Float16* src = A + (size_t)(rowBase + g * 8 + sub) * K + kt + gslot * 8;
        gload_lds16(src, (char*)ldsA + g * 1024);
      } else {
        int gb = g - BM / 8;
        const _Float16* src = B + (size_t)(colBase + gb * 8 + sub) * K + kt + gslot * 8;
        gload_lds16(src, (char*)ldsB + gb * 1024);
      }
    }
    __syncthreads();

    #pragma unroll
    for (int ks = 0; ks < 2; ++ks) {
      const int s = ks * 4 + q4;
      half8 a[4], b[4];
      #pragma unroll
      for (int m = 0; m < 4; ++m) {
        int row = wr + m * 16 + l15;
        a[m] = *(const half8*)((const char*)ldsA + row * 128 + ((s * 16) ^ ((row & 7) << 4)));
      }
      #pragma unroll
      for (int n = 0; n < 4; ++n) {
        int row = wc + n * 16 + l15;
        b[n] = *(const half8*)((const char*)ldsB + row * 128 + ((s * 16) ^ ((row & 7) << 4)));
      }
      #pragma unroll
      for (int m = 0; m < 4; ++m)
        #pragma unroll
        for (int n = 0; n < 4; ++n)
          acc[m][n] = __builtin_amdgcn_mfma_f32_16x16x32_f16(a[m], b[n], acc[m][n], 0, 0, 0);
    }
    __syncthreads();
  }

  #pragma unroll
  for (int m = 0; m < 4; ++m) {
    #pragma unroll
    for (int n = 0; n < 4; ++n) {
      int col = colBase + wc + n * 16 + l15;
      #pragma unroll
      for (int r = 0; r < 4; ++r) {
        int row = rowBase + wr + m * 16 + q4 * 4 + r;
        outp[(size_t)row * N + col] = acc[m][n][r];
      }
    }
  }
}

// ---------------- top-16 + scatter-softmax gates (radix-select) ----------------
__global__ __launch_bounds__(256) void topk_gates_kernel(const float* __restrict__ scores,
                                                         float* __restrict__ gates) {
  __shared__ uint32_t hist[4096];            // 16KB; reused as candidate store
  __shared__ uint32_t sA[256];
  __shared__ uint32_t av[16], ai[16];
  __shared__ uint32_t sk[KTOP], si[KTOP];
  __shared__ uint32_t cntA, cntC;
  __shared__ int s_p; __shared__ uint32_t s_above;
  __shared__ float gk[KTOP]; __shared__ float s_gother;

  const int tid  = threadIdx.x;
  const int lane = tid & 63;
  const int w    = tid >> 6;
  const float* srow = scores + (size_t)blockIdx.x * NKEYS;

  uint4 z4 = {0, 0, 0, 0};
  #pragma unroll
  for (int i = 0; i < 4; ++i) ((uint4*)hist)[tid + 256 * i] = z4;
  if (tid == 0) { cntA = 0; cntC = 0; }

  uint32_t key[16];
  const int base = (w << 10) + (lane << 4);
  {
    const float4* p4 = (const float4*)(srow + base);
    #pragma unroll
    for (int i = 0; i < 4; ++i) {
      float4 t = p4[i];
      float tv[4] = { t.x, t.y, t.z, t.w };
      #pragma unroll
      for (int c = 0; c < 4; ++c) {
        uint32_t u = __float_as_uint(tv[c]);
        key[i * 4 + c] = u ^ (uint32_t)(((int32_t)u >> 31) | 0x80000000);
      }
    }
  }
  __syncthreads();

  #pragma unroll
  for (int j = 0; j < 16; ++j) atomicAdd(&hist[key[j] >> 20], 1u);
  __syncthreads();

  uint32_t h[16];
  #pragma unroll
  for (int i = 0; i < 16; ++i) h[i] = hist[tid * 16 + i];
  uint32_t sfx[17]; sfx[16] = 0;
  #pragma unroll
  for (int i = 15; i >= 0; --i) sfx[i] = sfx[i + 1] + h[i];
  sA[tid] = sfx[0];
  __syncthreads();
  uint32_t s = sfx[0];
  #pragma unroll
  for (int off = 1; off < 256; off <<= 1) {
    uint32_t add = (tid + off < 256) ? sA[tid + off] : 0;
    __syncthreads();
    s += add; sA[tid] = s;
    __syncthreads();
  }
  const uint32_t exclHi = s - sfx[0];

  #pragma unroll
  for (int i = 0; i < 16; ++i) {
    uint32_t cg = exclHi + sfx[i + 1];
    if (cg < KTOP && cg + h[i] >= KTOP) { s_p = tid * 16 + i; s_above = cg; }
  }
  __syncthreads();
  const uint32_t p = (uint32_t)s_p;
  const uint32_t above = s_above;
  const uint32_t need = KTOP - above;

  uint32_t* ck = hist;
  uint32_t* ci = hist + 2048;
  #pragma unroll
  for (int j = 0; j < 16; ++j) {
    uint32_t b = key[j] >> 20;
    if (b >= p) {
      uint32_t idx = (uint32_t)(base + j);
      if (b > p) { uint32_t pos = atomicAdd(&cntA, 1u); av[pos] = key[j]; ai[pos] = idx; }
      else       { uint32_t pos = atomicAdd(&cntC, 1u); if (pos < 2048u) { ck[pos] = key[j]; ci[pos] = idx; } }
    }
  }
  __syncthreads();

  const uint32_t nA = cntA;
  if (tid < nA) { sk[tid] = av[tid]; si[tid] = ai[tid]; }

  if (w == 0) {
    const uint32_t nC = min(cntC, 2048u);
    for (uint32_t k = 0; k < need; ++k) {
      uint32_t bk = 0, bi = 0xFFFFFFFFu, bp = 0;
      for (uint32_t c = lane; c < nC; c += 64) {
        uint32_t kk = ck[c], ii = ci[c];
        if (kk > bk || (kk == bk && ii < bi)) { bk = kk; bi = ii; bp = c; }
      }
      #pragma unroll
      for (int off = 32; off >= 1; off >>= 1) {
        uint32_t ok = __shfl_down(bk, off);
        uint32_t oi = __shfl_down(bi, off);
        uint32_t op = __shfl_down(bp, off);
        if (ok > bk || (ok == bk && oi < bi)) { bk = ok; bi = oi; bp = op; }
      }
      bp = __shfl(bp, 0);
      if (lane == 0) { ck[bp] = 0; sk[nA + k] = bk; si[nA + k] = bi; }
    }
  }
  __syncthreads();

  if (tid == 0) {
    float f[KTOP]; float mx = 0.f;
    #pragma unroll
    for (int k = 0; k < KTOP; ++k) {
      uint32_t kk = sk[k];
      float fv = (kk & 0x80000000u) ? __uint_as_float(kk ^ 0x80000000u)
                                    : __uint_as_float(~kk);
      f[k] = fv; mx = fmaxf(mx, fv);
    }
    float eo = __expf(-mx);
    float Z = (float)(NKEYS - KTOP) * eo;
    float e[KTOP];
    #pragma unroll
    for (int k = 0; k < KTOP; ++k) { e[k] = __expf(f[k] - mx); Z += e[k]; }
    float inv = 1.f / Z;
    #pragma unroll
    for (int k = 0; k < KTOP; ++k) gk[k] = e[k] * inv;
    s_gother = eo * inv;
  }
  __syncthreads();

  float go = s_gother;
  float4 g4 = { go, go, go, go };
  float* grow = gates + (size_t)blockIdx.x * NKEYS;
  #pragma unroll
  for (int j = 0; j < 4; ++j) ((float4*)grow)[j * 256 + tid] = g4;
  __syncthreads();
  if (tid < KTOP) grow[si[tid]] = gk[tid];
}

extern "C" void kernel_launch(void* const* d_in, const int* in_sizes, int n_in,
                              void* d_out, int out_size, void* d_ws, size_t ws_size,
                              hipStream_t stream) {
  const float* x    = (const float*)d_in[0];
  const float* keys = (const float*)d_in[1];
  const float* W    = (const float*)d_in[2];
  const float* bias = (const float*)d_in[3];
  (void)in_sizes; (void)n_in; (void)out_size; (void)ws_size;

  float* gates  = (float*)d_out;
  float* scores = (float*)d_out + (size_t)BS_T * NKEYS;

  _Float16* W_h = (_Float16*)d_ws;                 // 4 MB
  _Float16* k_h = W_h + (size_t)KDIM * XDIM;       // 4 MB
  _Float16* q_h = k_h + (size_t)NKEYS * KDIM;      // 16 MB

  cvt_f32_f16_v<<<dim3(1024), dim3(256), 0, stream>>>(W, W_h, KDIM * XDIM / 8);
  cvt_f32_f16_v<<<dim3(1024), dim3(256), 0, stream>>>(keys, k_h, NKEYS * KDIM / 8);

  // query = x @ W^T + b -> q_h (fp16); x read ONCE, coalesced, counted-vmcnt pipe
  gemm1_fused<<<dim3(BS_T / 64), dim3(512), 0, stream>>>(x, W_h, bias, q_h);

  // scores = q @ keys^T -> fp32. 128x128 tiles, 4 waves (2x2), grid 4096
  gemm16<128, 128, 4, 2, 3><<<dim3((BS_T / 128) * (NKEYS / 128)), dim3(256), 0, stream>>>(
      q_h, k_h, scores, BS_T, NKEYS, KDIM, NKEYS / 128);

  topk_gates_kernel<<<dim3(BS_T), dim3(256), 0, stream>>>(scores, gates);
}

// Round 8
// 384.690 us; speedup vs baseline: 1.8551x; 1.0792x over previous
//
#include <hip/hip_runtime.h>
#include <stdint.h>

#define BS_T   16384
#define XDIM   4096
#define KDIM   512
#define NKEYS  4096
#define KTOP   16

typedef _Float16 half8  __attribute__((ext_vector_type(8)));
typedef float    floatx4 __attribute__((ext_vector_type(4)));

// async global->LDS, 16B per lane; LDS dest is wave-uniform base + lane*16
__device__ static inline void gload_lds16(const void* g, void* l) {
  __builtin_amdgcn_global_load_lds(
      (const __attribute__((address_space(1))) uint32_t*)(uintptr_t)g,
      (__attribute__((address_space(3))) uint32_t*)(uint32_t)(uintptr_t)l,
      16, 0, 0);
}

// ---------------- fp32 -> fp16 convert (vectorized, grid-stride) ----------------
__global__ __launch_bounds__(256) void cvt_f32_f16_v(const float* __restrict__ in,
                                                     _Float16* __restrict__ out, int n8) {
  int stride = gridDim.x * 256;
  for (int i = blockIdx.x * 256 + threadIdx.x; i < n8; i += stride) {
    float4 v0 = ((const float4*)in)[2 * i];
    float4 v1 = ((const float4*)in)[2 * i + 1];
    half8 h = { (_Float16)v0.x, (_Float16)v0.y, (_Float16)v0.z, (_Float16)v0.w,
                (_Float16)v1.x, (_Float16)v1.y, (_Float16)v1.z, (_Float16)v1.w };
    ((half8*)out)[i] = h;
  }
}

// ---------------- GEMM1 fused v4: Q[M,512] = cvt16(X[M,4096]) @ W16^T + b ----------
// BM=64, BN=256 (2 col-tiles; x read 2x = 512 MB), 256 threads, 4 waves x 64x64
// wave-tile. LDS = A-dbuf 16KB + B-dbuf 64KB = 80KB -> 2 blocks/CU: the sibling
// block fills the per-step barrier drain (m114 implicit overlap) that made the
// 1-block/CU read-once variant latency-bound. Plain v1-style schedule, no manual
// waitcnt (R7 lesson). A: coalesced fp32 load -> in-reg cvt -> swizzled ds_write.
__global__ __launch_bounds__(256, 2)
void gemm1_fused(const float* __restrict__ X, const _Float16* __restrict__ Wh,
                 const float* __restrict__ bias, _Float16* __restrict__ Q) {
  __shared__ __align__(16) _Float16 ldsA[2][64 * 64];    // 2 x 8 KB
  __shared__ __align__(16) _Float16 ldsB[2][256 * 64];   // 2 x 32 KB

  const int tid  = threadIdx.x;
  const int lane = tid & 63;
  const int wid  = tid >> 6;            // 0..3
  const int cpx  = gridDim.x >> 3;
  const int bid  = (blockIdx.x & 7) * cpx + (blockIdx.x >> 3);
  const int rowBase = (bid >> 1) * 64;
  const int colBase = (bid & 1) * 256;
  const int wc  = wid * 64;             // wave's 64-col slice within the 256 tile
  const int l15 = lane & 15;
  const int q4  = lane >> 4;
  const int sub   = lane >> 3;
  const int gslot = (lane & 7) ^ sub;   // pre-swizzled global slot for gload_lds

  // A staging: 2 half8/thread; chunk0: row=tid>>3, slot=tid&7; chunk1: row+32
  const int arow  = tid >> 3;
  const int aslot = tid & 7;
  const float* aSrc0 = X + (size_t)(rowBase + arow) * XDIM + aslot * 8;
  const float* aSrc1 = aSrc0 + (size_t)32 * XDIM;
  const int aoff = arow * 128 + ((aslot * 16) ^ ((arow & 7) << 4));
  char* const aD0 = (char*)&ldsA[0][0] + aoff;   // +32 rows = +4096 bytes
  char* const aD1 = (char*)&ldsA[1][0] + aoff;
  // B staging: wave w stages groups w*8..w*8+7 (rows wc..wc+63 of the col-tile)
  const _Float16* const bSrc = Wh + (size_t)(colBase + wc + sub) * XDIM + gslot * 8;
  char* const bD0 = (char*)&ldsB[0][0] + wid * 8192;
  char* const bD1 = (char*)&ldsB[1][0] + wid * 8192;

  floatx4 acc[4][4];
  #pragma unroll
  for (int m = 0; m < 4; ++m)
    #pragma unroll
    for (int n = 0; n < 4; ++n)
      acc[m][n] = (floatx4)0.0f;

  auto stageB = [&](int kt, char* bd) {
    #pragma unroll
    for (int i = 0; i < 8; ++i)
      gload_lds16(bSrc + (size_t)i * 8 * XDIM + kt, bd + i * 1024);
  };
  auto writeA = [&](char* ad, float4 v00, float4 v01, float4 v10, float4 v11) {
    half8 h0 = { (_Float16)v00.x, (_Float16)v00.y, (_Float16)v00.z, (_Float16)v00.w,
                 (_Float16)v01.x, (_Float16)v01.y, (_Float16)v01.z, (_Float16)v01.w };
    half8 h1 = { (_Float16)v10.x, (_Float16)v10.y, (_Float16)v10.z, (_Float16)v10.w,
                 (_Float16)v11.x, (_Float16)v11.y, (_Float16)v11.z, (_Float16)v11.w };
    *(half8*)ad = h0;
    *(half8*)(ad + 4096) = h1;          // row+32: same swizzle phase
  };
  auto compute = [&](const char* bA, const char* bB) {
    #pragma unroll
    for (int ks = 0; ks < 2; ++ks) {
      const int s = ks * 4 + q4;
      half8 a[4], b[4];
      #pragma unroll
      for (int m = 0; m < 4; ++m) {
        int row = m * 16 + l15;
        a[m] = *(const half8*)(bA + row * 128 + ((s * 16) ^ ((row & 7) << 4)));
      }
      #pragma unroll
      for (int n = 0; n < 4; ++n) {
        int row = wc + n * 16 + l15;
        b[n] = *(const half8*)(bB + row * 128 + ((s * 16) ^ ((row & 7) << 4)));
      }
      #pragma unroll
      for (int m = 0; m < 4; ++m)
        #pragma unroll
        for (int n = 0; n < 4; ++n)
          acc[m][n] = __builtin_amdgcn_mfma_f32_16x16x32_f16(a[m], b[n], acc[m][n], 0, 0, 0);
    }
  };

  // prologue: stage tile 0 into buf 0
  {
    float4 v00 = *(const float4*)(aSrc0);
    float4 v01 = *(const float4*)(aSrc0 + 4);
    float4 v10 = *(const float4*)(aSrc1);
    float4 v11 = *(const float4*)(aSrc1 + 4);
    stageB(0, bD0);
    writeA(aD0, v00, v01, v10, v11);
  }
  __syncthreads();

  #pragma unroll 2
  for (int t = 0; t < 64; ++t) {
    const int pc = t & 1;
    const char* bA = pc ? (const char*)&ldsA[1][0] : (const char*)&ldsA[0][0];
    const char* bB = pc ? (const char*)&ldsB[1][0] : (const char*)&ldsB[0][0];
    char* adN = pc ? aD0 : aD1;
    char* bdN = pc ? bD0 : bD1;

    float4 v00, v01, v10, v11;
    if (t < 63) {
      const int ktn = (t + 1) * 64;
      v00 = *(const float4*)(aSrc0 + ktn);
      v01 = *(const float4*)(aSrc0 + ktn + 4);
      v10 = *(const float4*)(aSrc1 + ktn);
      v11 = *(const float4*)(aSrc1 + ktn + 4);
      stageB(ktn, bdN);
    }
    compute(bA, bB);
    if (t < 63) writeA(adN, v00, v01, v10, v11);
    __syncthreads();
  }

  // epilogue: C/D layout col=lane&15, row=(lane>>4)*4+r; fused bias + fp16 store
  #pragma unroll
  for (int m = 0; m < 4; ++m) {
    #pragma unroll
    for (int n = 0; n < 4; ++n) {
      int col = colBase + wc + n * 16 + l15;
      float bv = bias[col];
      #pragma unroll
      for (int r = 0; r < 4; ++r) {
        int row = rowBase + m * 16 + q4 * 4 + r;
        Q[(size_t)row * KDIM + col] = (_Float16)(acc[m][n][r] + bv);
      }
    }
  }
}

// ---------------- NT GEMM2: C[M,N] = A[M,K] * B[N,K]^T, fp16 in, fp32 out ----------
template<int BM, int BN, int WAVES, int WGN, int MINW>
__global__ __launch_bounds__(WAVES * 64, MINW)
void gemm16(const _Float16* __restrict__ A, const _Float16* __restrict__ B,
            float* __restrict__ outp, int M, int N, int K, int nCol) {
  __shared__ __align__(16) _Float16 ldsA[BM * 64];
  __shared__ __align__(16) _Float16 ldsB[BN * 64];

  const int tid = threadIdx.x;
  const int cpx = gridDim.x >> 3;
  const int bid = (blockIdx.x & 7) * cpx + (blockIdx.x >> 3);
  const int rowBase = (bid / nCol) * BM;
  const int colBase = (bid % nCol) * BN;
  const int lane = tid & 63;
  const int wid  = tid >> 6;
  const int wr = (wid / WGN) * 64;
  const int wc = (wid % WGN) * 64;
  const int l15 = lane & 15;
  const int q4  = lane >> 4;

  const int sub   = lane >> 3;
  const int gslot = (lane & 7) ^ sub;

  constexpr int GROUPS = (BM + BN) / 8;
  constexpr int GPW    = GROUPS / WAVES;

  floatx4 acc[4][4];
  #pragma unroll
  for (int m = 0; m < 4; ++m)
    #pragma unroll
    for (int n = 0; n < 4; ++n)
      acc[m][n] = (floatx4)0.0f;

  for (int kt = 0; kt < K; kt += 64) {
    #pragma unroll
    for (int i = 0; i < GPW; ++i) {
      int g = wid * GPW + i;
      if (g < BM / 8) {
        const _Float16* src = A + (size_t)(rowBase + g * 8 + sub) * K + kt + gslot * 8;
        gload_lds16(src, (char*)ldsA + g * 1024);
      } else {
        int gb = g - BM / 8;
        const _Float16* src = B + (size_t)(colBase + gb * 8 + sub) * K + kt + gslot * 8;
        gload_lds16(src, (char*)ldsB + gb * 1024);
      }
    }
    __syncthreads();

    #pragma unroll
    for (int ks = 0; ks < 2; ++ks) {
      const int s = ks * 4 + q4;
      half8 a[4], b[4];
      #pragma unroll
      for (int m = 0; m < 4; ++m) {
        int row = wr + m * 16 + l15;
        a[m] = *(const half8*)((const char*)ldsA + row * 128 + ((s * 16) ^ ((row & 7) << 4)));
      }
      #pragma unroll
      for (int n = 0; n < 4; ++n) {
        int row = wc + n * 16 + l15;
        b[n] = *(const half8*)((const char*)ldsB + row * 128 + ((s * 16) ^ ((row & 7) << 4)));
      }
      #pragma unroll
      for (int m = 0; m < 4; ++m)
        #pragma unroll
        for (int n = 0; n < 4; ++n)
          acc[m][n] = __builtin_amdgcn_mfma_f32_16x16x32_f16(a[m], b[n], acc[m][n], 0, 0, 0);
    }
    __syncthreads();
  }

  #pragma unroll
  for (int m = 0; m < 4; ++m) {
    #pragma unroll
    for (int n = 0; n < 4; ++n) {
      int col = colBase + wc + n * 16 + l15;
      #pragma unroll
      for (int r = 0; r < 4; ++r) {
        int row = rowBase + wr + m * 16 + q4 * 4 + r;
        outp[(size_t)row * N + col] = acc[m][n][r];
      }
    }
  }
}

// ---------------- top-16 + scatter-softmax gates (radix-select) ----------------
__global__ __launch_bounds__(256) void topk_gates_kernel(const float* __restrict__ scores,
                                                         float* __restrict__ gates) {
  __shared__ uint32_t hist[4096];            // 16KB; reused as candidate store
  __shared__ uint32_t sA[256];
  __shared__ uint32_t av[16], ai[16];
  __shared__ uint32_t sk[KTOP], si[KTOP];
  __shared__ uint32_t cntA, cntC;
  __shared__ int s_p; __shared__ uint32_t s_above;
  __shared__ float gk[KTOP]; __shared__ float s_gother;

  const int tid  = threadIdx.x;
  const int lane = tid & 63;
  const int w    = tid >> 6;
  const float* srow = scores + (size_t)blockIdx.x * NKEYS;

  uint4 z4 = {0, 0, 0, 0};
  #pragma unroll
  for (int i = 0; i < 4; ++i) ((uint4*)hist)[tid + 256 * i] = z4;
  if (tid == 0) { cntA = 0; cntC = 0; }

  uint32_t key[16];
  const int base = (w << 10) + (lane << 4);
  {
    const float4* p4 = (const float4*)(srow + base);
    #pragma unroll
    for (int i = 0; i < 4; ++i) {
      float4 t = p4[i];
      float tv[4] = { t.x, t.y, t.z, t.w };
      #pragma unroll
      for (int c = 0; c < 4; ++c) {
        uint32_t u = __float_as_uint(tv[c]);
        key[i * 4 + c] = u ^ (uint32_t)(((int32_t)u >> 31) | 0x80000000);
      }
    }
  }
  __syncthreads();

  #pragma unroll
  for (int j = 0; j < 16; ++j) atomicAdd(&hist[key[j] >> 20], 1u);
  __syncthreads();

  uint32_t h[16];
  #pragma unroll
  for (int i = 0; i < 16; ++i) h[i] = hist[tid * 16 + i];
  uint32_t sfx[17]; sfx[16] = 0;
  #pragma unroll
  for (int i = 15; i >= 0; --i) sfx[i] = sfx[i + 1] + h[i];
  sA[tid] = sfx[0];
  __syncthreads();
  uint32_t s = sfx[0];
  #pragma unroll
  for (int off = 1; off < 256; off <<= 1) {
    uint32_t add = (tid + off < 256) ? sA[tid + off] : 0;
    __syncthreads();
    s += add; sA[tid] = s;
    __syncthreads();
  }
  const uint32_t exclHi = s - sfx[0];

  #pragma unroll
  for (int i = 0; i < 16; ++i) {
    uint32_t cg = exclHi + sfx[i + 1];
    if (cg < KTOP && cg + h[i] >= KTOP) { s_p = tid * 16 + i; s_above = cg; }
  }
  __syncthreads();
  const uint32_t p = (uint32_t)s_p;
  const uint32_t above = s_above;
  const uint32_t need = KTOP - above;

  uint32_t* ck = hist;
  uint32_t* ci = hist + 2048;
  #pragma unroll
  for (int j = 0; j < 16; ++j) {
    uint32_t b = key[j] >> 20;
    if (b >= p) {
      uint32_t idx = (uint32_t)(base + j);
      if (b > p) { uint32_t pos = atomicAdd(&cntA, 1u); av[pos] = key[j]; ai[pos] = idx; }
      else       { uint32_t pos = atomicAdd(&cntC, 1u); if (pos < 2048u) { ck[pos] = key[j]; ci[pos] = idx; } }
    }
  }
  __syncthreads();

  const uint32_t nA = cntA;
  if (tid < nA) { sk[tid] = av[tid]; si[tid] = ai[tid]; }

  if (w == 0) {
    const uint32_t nC = min(cntC, 2048u);
    for (uint32_t k = 0; k < need; ++k) {
      uint32_t bk = 0, bi = 0xFFFFFFFFu, bp = 0;
      for (uint32_t c = lane; c < nC; c += 64) {
        uint32_t kk = ck[c], ii = ci[c];
        if (kk > bk || (kk == bk && ii < bi)) { bk = kk; bi = ii; bp = c; }
      }
      #pragma unroll
      for (int off = 32; off >= 1; off >>= 1) {
        uint32_t ok = __shfl_down(bk, off);
        uint32_t oi = __shfl_down(bi, off);
        uint32_t op = __shfl_down(bp, off);
        if (ok > bk || (ok == bk && oi < bi)) { bk = ok; bi = oi; bp = op; }
      }
      bp = __shfl(bp, 0);
      if (lane == 0) { ck[bp] = 0; sk[nA + k] = bk; si[nA + k] = bi; }
    }
  }
  __syncthreads();

  if (tid == 0) {
    float f[KTOP]; float mx = 0.f;
    #pragma unroll
    for (int k = 0; k < KTOP; ++k) {
      uint32_t kk = sk[k];
      float fv = (kk & 0x80000000u) ? __uint_as_float(kk ^ 0x80000000u)
                                    : __uint_as_float(~kk);
      f[k] = fv; mx = fmaxf(mx, fv);
    }
    float eo = __expf(-mx);
    float Z = (float)(NKEYS - KTOP) * eo;
    float e[KTOP];
    #pragma unroll
    for (int k = 0; k < KTOP; ++k) { e[k] = __expf(f[k] - mx); Z += e[k]; }
    float inv = 1.f / Z;
    #pragma unroll
    for (int k = 0; k < KTOP; ++k) gk[k] = e[k] * inv;
    s_gother = eo * inv;
  }
  __syncthreads();

  float go = s_gother;
  float4 g4 = { go, go, go, go };
  float* grow = gates + (size_t)blockIdx.x * NKEYS;
  #pragma unroll
  for (int j = 0; j < 4; ++j) ((float4*)grow)[j * 256 + tid] = g4;
  __syncthreads();
  if (tid < KTOP) grow[si[tid]] = gk[tid];
}

extern "C" void kernel_launch(void* const* d_in, const int* in_sizes, int n_in,
                              void* d_out, int out_size, void* d_ws, size_t ws_size,
                              hipStream_t stream) {
  const float* x    = (const float*)d_in[0];
  const float* keys = (const float*)d_in[1];
  const float* W    = (const float*)d_in[2];
  const float* bias = (const float*)d_in[3];
  (void)in_sizes; (void)n_in; (void)out_size; (void)ws_size;

  float* gates  = (float*)d_out;
  float* scores = (float*)d_out + (size_t)BS_T * NKEYS;

  _Float16* W_h = (_Float16*)d_ws;                 // 4 MB
  _Float16* k_h = W_h + (size_t)KDIM * XDIM;       // 4 MB
  _Float16* q_h = k_h + (size_t)NKEYS * KDIM;      // 16 MB

  cvt_f32_f16_v<<<dim3(1024), dim3(256), 0, stream>>>(W, W_h, KDIM * XDIM / 8);
  cvt_f32_f16_v<<<dim3(1024), dim3(256), 0, stream>>>(keys, k_h, NKEYS * KDIM / 8);

  // query = x @ W^T + b -> q_h (fp16). BM=64/BN=256, 2 blocks/CU, grid 512
  gemm1_fused<<<dim3((BS_T / 64) * 2), dim3(256), 0, stream>>>(x, W_h, bias, q_h);

  // scores = q @ keys^T -> fp32. 128x128 tiles, 4 waves (2x2), grid 4096
  gemm16<128, 128, 4, 2, 3><<<dim3((BS_T / 128) * (NKEYS / 128)), dim3(256), 0, stream>>>(
      q_h, k_h, scores, BS_T, NKEYS, KDIM, NKEYS / 128);

  topk_gates_kernel<<<dim3(BS_T), dim3(256), 0, stream>>>(scores, gates);
}

// Round 9
// 359.860 us; speedup vs baseline: 1.9831x; 1.0690x over previous
//
#include <hip/hip_runtime.h>
#include <stdint.h>

#define BS_T   16384
#define XDIM   4096
#define KDIM   512
#define NKEYS  4096
#define KTOP   16

typedef _Float16 half8  __attribute__((ext_vector_type(8)));
typedef float    floatx4 __attribute__((ext_vector_type(4)));

// async global->LDS, 16B per lane; LDS dest is wave-uniform base + lane*16
__device__ static inline void gload_lds16(const void* g, void* l) {
  __builtin_amdgcn_global_load_lds(
      (const __attribute__((address_space(1))) uint32_t*)(uintptr_t)g,
      (__attribute__((address_space(3))) uint32_t*)(uint32_t)(uintptr_t)l,
      16, 0, 0);
}

#define FULL_BAR() do { __builtin_amdgcn_sched_barrier(0); \
                        __builtin_amdgcn_s_barrier(); \
                        __builtin_amdgcn_sched_barrier(0); } while (0)

// ---------------- fp32 -> fp16 convert (vectorized, grid-stride) ----------------
__global__ __launch_bounds__(256) void cvt_f32_f16_v(const float* __restrict__ in,
                                                     _Float16* __restrict__ out, int n8) {
  int stride = gridDim.x * 256;
  for (int i = blockIdx.x * 256 + threadIdx.x; i < n8; i += stride) {
    float4 v0 = ((const float4*)in)[2 * i];
    float4 v1 = ((const float4*)in)[2 * i + 1];
    half8 h = { (_Float16)v0.x, (_Float16)v0.y, (_Float16)v0.z, (_Float16)v0.w,
                (_Float16)v1.x, (_Float16)v1.y, (_Float16)v1.z, (_Float16)v1.w };
    ((half8*)out)[i] = h;
  }
}

// ---------------- GEMM1 fused v4 (unchanged from R8) ----------------
__global__ __launch_bounds__(256, 2)
void gemm1_fused(const float* __restrict__ X, const _Float16* __restrict__ Wh,
                 const float* __restrict__ bias, _Float16* __restrict__ Q) {
  __shared__ __align__(16) _Float16 ldsA[2][64 * 64];
  __shared__ __align__(16) _Float16 ldsB[2][256 * 64];

  const int tid  = threadIdx.x;
  const int lane = tid & 63;
  const int wid  = tid >> 6;
  const int cpx  = gridDim.x >> 3;
  const int bid  = (blockIdx.x & 7) * cpx + (blockIdx.x >> 3);
  const int rowBase = (bid >> 1) * 64;
  const int colBase = (bid & 1) * 256;
  const int wc  = wid * 64;
  const int l15 = lane & 15;
  const int q4  = lane >> 4;
  const int sub   = lane >> 3;
  const int gslot = (lane & 7) ^ sub;

  const int arow  = tid >> 3;
  const int aslot = tid & 7;
  const float* aSrc0 = X + (size_t)(rowBase + arow) * XDIM + aslot * 8;
  const float* aSrc1 = aSrc0 + (size_t)32 * XDIM;
  const int aoff = arow * 128 + ((aslot * 16) ^ ((arow & 7) << 4));
  char* const aD0 = (char*)&ldsA[0][0] + aoff;
  char* const aD1 = (char*)&ldsA[1][0] + aoff;
  const _Float16* const bSrc = Wh + (size_t)(colBase + wc + sub) * XDIM + gslot * 8;
  char* const bD0 = (char*)&ldsB[0][0] + wid * 8192;
  char* const bD1 = (char*)&ldsB[1][0] + wid * 8192;

  floatx4 acc[4][4];
  #pragma unroll
  for (int m = 0; m < 4; ++m)
    #pragma unroll
    for (int n = 0; n < 4; ++n)
      acc[m][n] = (floatx4)0.0f;

  auto stageB = [&](int kt, char* bd) {
    #pragma unroll
    for (int i = 0; i < 8; ++i)
      gload_lds16(bSrc + (size_t)i * 8 * XDIM + kt, bd + i * 1024);
  };
  auto writeA = [&](char* ad, float4 v00, float4 v01, float4 v10, float4 v11) {
    half8 h0 = { (_Float16)v00.x, (_Float16)v00.y, (_Float16)v00.z, (_Float16)v00.w,
                 (_Float16)v01.x, (_Float16)v01.y, (_Float16)v01.z, (_Float16)v01.w };
    half8 h1 = { (_Float16)v10.x, (_Float16)v10.y, (_Float16)v10.z, (_Float16)v10.w,
                 (_Float16)v11.x, (_Float16)v11.y, (_Float16)v11.z, (_Float16)v11.w };
    *(half8*)ad = h0;
    *(half8*)(ad + 4096) = h1;
  };
  auto compute = [&](const char* bA, const char* bB) {
    #pragma unroll
    for (int ks = 0; ks < 2; ++ks) {
      const int s = ks * 4 + q4;
      half8 a[4], b[4];
      #pragma unroll
      for (int m = 0; m < 4; ++m) {
        int row = m * 16 + l15;
        a[m] = *(const half8*)(bA + row * 128 + ((s * 16) ^ ((row & 7) << 4)));
      }
      #pragma unroll
      for (int n = 0; n < 4; ++n) {
        int row = wc + n * 16 + l15;
        b[n] = *(const half8*)(bB + row * 128 + ((s * 16) ^ ((row & 7) << 4)));
      }
      #pragma unroll
      for (int m = 0; m < 4; ++m)
        #pragma unroll
        for (int n = 0; n < 4; ++n)
          acc[m][n] = __builtin_amdgcn_mfma_f32_16x16x32_f16(a[m], b[n], acc[m][n], 0, 0, 0);
    }
  };

  {
    float4 v00 = *(const float4*)(aSrc0);
    float4 v01 = *(const float4*)(aSrc0 + 4);
    float4 v10 = *(const float4*)(aSrc1);
    float4 v11 = *(const float4*)(aSrc1 + 4);
    stageB(0, bD0);
    writeA(aD0, v00, v01, v10, v11);
  }
  __syncthreads();

  #pragma unroll 2
  for (int t = 0; t < 64; ++t) {
    const int pc = t & 1;
    const char* bA = pc ? (const char*)&ldsA[1][0] : (const char*)&ldsA[0][0];
    const char* bB = pc ? (const char*)&ldsB[1][0] : (const char*)&ldsB[0][0];
    char* adN = pc ? aD0 : aD1;
    char* bdN = pc ? bD0 : bD1;

    float4 v00, v01, v10, v11;
    if (t < 63) {
      const int ktn = (t + 1) * 64;
      v00 = *(const float4*)(aSrc0 + ktn);
      v01 = *(const float4*)(aSrc0 + ktn + 4);
      v10 = *(const float4*)(aSrc1 + ktn);
      v11 = *(const float4*)(aSrc1 + ktn + 4);
      stageB(ktn, bdN);
    }
    compute(bA, bB);
    if (t < 63) writeA(adN, v00, v01, v10, v11);
    __syncthreads();
  }

  #pragma unroll
  for (int m = 0; m < 4; ++m) {
    #pragma unroll
    for (int n = 0; n < 4; ++n) {
      int col = colBase + wc + n * 16 + l15;
      float bv = bias[col];
      #pragma unroll
      for (int r = 0; r < 4; ++r) {
        int row = rowBase + m * 16 + q4 * 4 + r;
        Q[(size_t)row * KDIM + col] = (_Float16)(acc[m][n][r] + bv);
      }
    }
  }
}

// ---------------- GEMM2 pipelined: scores = q_h @ keys_h^T ----------------
// 256x256 tile, BK=64, NT=8 K-tiles, 8 waves (2M x 4N, 128x64 per wave).
// Counted-vmcnt schedule (T3/T4): 4 phases per K-tile, each {ds_read subtile +
// stage-issue -> s_barrier -> lgkmcnt(0) -> setprio(1)+16 MFMA -> s_barrier};
// ONE vmcnt(8) per K-tile (8 loads = 1 K-tile stay in flight across barriers).
// Stage placement derived so every overwritten LDS region's last reader drained
// behind a barrier: P2 stages B(t+2)h0 (B h0 last read P1), P3 stages B(t+2)h1
// (last read P1), P4 stages A(t+2) h0+h1 (A last read P3). Ring-of-2 buffers.
__global__ __launch_bounds__(512, 2)
void gemm2_pipe(const _Float16* __restrict__ Aq, const _Float16* __restrict__ Bk,
                float* __restrict__ outp) {
  __shared__ __align__(16) _Float16 ldsA[2][256 * 64];   // 2 x 32 KB
  __shared__ __align__(16) _Float16 ldsB[2][256 * 64];   // 2 x 32 KB

  const int tid  = threadIdx.x;
  const int lane = tid & 63;
  const int wid  = tid >> 6;            // 0..7
  const int cpx  = gridDim.x >> 3;
  const int bid  = (blockIdx.x & 7) * cpx + (blockIdx.x >> 3);
  const int nCol = NKEYS / 256;         // 16
  const int rowBase = (bid / nCol) * 256;
  const int colBase = (bid % nCol) * 256;
  const int wm = wid >> 2;              // 0..1 -> M offset wm*128
  const int wn = wid & 3;               // 0..3 -> N offset wn*64
  const int l15 = lane & 15;
  const int q4  = lane >> 4;
  const int sub   = lane >> 3;
  const int gslot = (lane & 7) ^ sub;

  const _Float16* aSrc = Aq + (size_t)rowBase * KDIM;
  const _Float16* bSrc = Bk + (size_t)colBase * KDIM;

  // stage one half-tile (128 rows x 64 k): 16 groups of 8 rows; wave stages 2
  auto stageHalf = [&](const _Float16* src, char* ldsbase, int kt, int h) {
    #pragma unroll
    for (int j = 0; j < 2; ++j) {
      int g = h * 16 + wid * 2 + j;
      gload_lds16(src + (size_t)(g * 8 + sub) * KDIM + kt + gslot * 8,
                  ldsbase + g * 1024);
    }
  };
  auto ld8 = [&](const char* base, int row, int s) {
    return *(const half8*)(base + row * 128 + ((s * 16) ^ ((row & 7) << 4)));
  };

  floatx4 acc[8][4];
  #pragma unroll
  for (int m = 0; m < 8; ++m)
    #pragma unroll
    for (int n = 0; n < 4; ++n)
      acc[m][n] = (floatx4)0.0f;

  // prologue: K-tiles 0 and 1 fully staged; wait for tile 0 (8 newest ok)
  stageHalf(aSrc, (char*)ldsA[0], 0, 0);
  stageHalf(aSrc, (char*)ldsA[0], 0, 1);
  stageHalf(bSrc, (char*)ldsB[0], 0, 0);
  stageHalf(bSrc, (char*)ldsB[0], 0, 1);
  stageHalf(aSrc, (char*)ldsA[1], 64, 0);
  stageHalf(aSrc, (char*)ldsA[1], 64, 1);
  stageHalf(bSrc, (char*)ldsB[1], 64, 0);
  stageHalf(bSrc, (char*)ldsB[1], 64, 1);
  asm volatile("s_waitcnt vmcnt(8)" ::: "memory");
  FULL_BAR();

  for (int t = 0; t < 8; ++t) {
    const char* bA = (const char*)ldsA[t & 1];
    const char* bB = (const char*)ldsB[t & 1];
    char* sA = (char*)ldsA[t & 1];      // stage target for K-tile t+2 (same parity)
    char* sB = (char*)ldsB[t & 1];
    const int ktn = (t + 2) * 64;
    const bool st = (t < 6);

    half8 a[4][2], b[4][2];

    // ---- P1: read A-lo (m0-3) + all B; MFMA mlo x nlo ----
    #pragma unroll
    for (int m = 0; m < 4; ++m)
      #pragma unroll
      for (int kk = 0; kk < 2; ++kk)
        a[m][kk] = ld8(bA, wm * 128 + m * 16 + l15, kk * 4 + q4);
    #pragma unroll
    for (int n = 0; n < 4; ++n)
      #pragma unroll
      for (int kk = 0; kk < 2; ++kk)
        b[n][kk] = ld8(bB, wn * 64 + n * 16 + l15, kk * 4 + q4);
    FULL_BAR();
    asm volatile("s_waitcnt lgkmcnt(0)" ::: "memory");
    __builtin_amdgcn_sched_barrier(0);
    __builtin_amdgcn_s_setprio(1);
    #pragma unroll
    for (int m = 0; m < 4; ++m)
      #pragma unroll
      for (int n = 0; n < 2; ++n)
        #pragma unroll
        for (int kk = 0; kk < 2; ++kk)
          acc[m][n] = __builtin_amdgcn_mfma_f32_16x16x32_f16(a[m][kk], b[n][kk], acc[m][n], 0, 0, 0);
    __builtin_amdgcn_s_setprio(0);
    FULL_BAR();

    // ---- P2: stage B(t+2) h0; MFMA mlo x nhi ----
    if (st) stageHalf(bSrc, sB, ktn, 0);
    __builtin_amdgcn_sched_barrier(0);
    __builtin_amdgcn_s_setprio(1);
    #pragma unroll
    for (int m = 0; m < 4; ++m)
      #pragma unroll
      for (int n = 2; n < 4; ++n)
        #pragma unroll
        for (int kk = 0; kk < 2; ++kk)
          acc[m][n] = __builtin_amdgcn_mfma_f32_16x16x32_f16(a[m][kk], b[n][kk], acc[m][n], 0, 0, 0);
    __builtin_amdgcn_s_setprio(0);
    FULL_BAR();

    // ---- P3: read A-hi (m4-7); stage B(t+2) h1; MFMA mhi x nlo ----
    #pragma unroll
    for (int m = 0; m < 4; ++m)
      #pragma unroll
      for (int kk = 0; kk < 2; ++kk)
        a[m][kk] = ld8(bA, wm * 128 + (m + 4) * 16 + l15, kk * 4 + q4);
    if (st) stageHalf(bSrc, sB, ktn, 1);
    FULL_BAR();
    asm volatile("s_waitcnt lgkmcnt(0)" ::: "memory");
    __builtin_amdgcn_sched_barrier(0);
    __builtin_amdgcn_s_setprio(1);
    #pragma unroll
    for (int m = 0; m < 4; ++m)
      #pragma unroll
      for (int n = 0; n < 2; ++n)
        #pragma unroll
        for (int kk = 0; kk < 2; ++kk)
          acc[m + 4][n] = __builtin_amdgcn_mfma_f32_16x16x32_f16(a[m][kk], b[n][kk], acc[m + 4][n], 0, 0, 0);
    __builtin_amdgcn_s_setprio(0);
    FULL_BAR();

    // ---- P4: stage A(t+2) h0+h1; MFMA mhi x nhi; K-tile vmcnt gate ----
    if (st) { stageHalf(aSrc, sA, ktn, 0); stageHalf(aSrc, sA, ktn, 1); }
    __builtin_amdgcn_sched_barrier(0);
    __builtin_amdgcn_s_setprio(1);
    #pragma unroll
    for (int m = 0; m < 4; ++m)
      #pragma unroll
      for (int n = 2; n < 4; ++n)
        #pragma unroll
        for (int kk = 0; kk < 2; ++kk)
          acc[m + 4][n] = __builtin_amdgcn_mfma_f32_16x16x32_f16(a[m][kk], b[n][kk], acc[m + 4][n], 0, 0, 0);
    __builtin_amdgcn_s_setprio(0);
    __builtin_amdgcn_sched_barrier(0);
    if (t < 6)      asm volatile("s_waitcnt vmcnt(8)" ::: "memory");
    else if (t == 6) asm volatile("s_waitcnt vmcnt(0)" ::: "memory");
    FULL_BAR();
  }

  // epilogue: C/D layout col=lane&15, row=(lane>>4)*4+r
  #pragma unroll
  for (int m = 0; m < 8; ++m) {
    #pragma unroll
    for (int n = 0; n < 4; ++n) {
      int col = colBase + wn * 64 + n * 16 + l15;
      #pragma unroll
      for (int r = 0; r < 4; ++r) {
        int row = rowBase + wm * 128 + m * 16 + q4 * 4 + r;
        outp[(size_t)row * NKEYS + col] = acc[m][n][r];
      }
    }
  }
}

// ---------------- top-16 + scatter-softmax gates (radix-select) ----------------
__global__ __launch_bounds__(256) void topk_gates_kernel(const float* __restrict__ scores,
                                                         float* __restrict__ gates) {
  __shared__ uint32_t hist[4096];
  __shared__ uint32_t sA[256];
  __shared__ uint32_t av[16], ai[16];
  __shared__ uint32_t sk[KTOP], si[KTOP];
  __shared__ uint32_t cntA, cntC;
  __shared__ int s_p; __shared__ uint32_t s_above;
  __shared__ float gk[KTOP]; __shared__ float s_gother;

  const int tid  = threadIdx.x;
  const int lane = tid & 63;
  const int w    = tid >> 6;
  const float* srow = scores + (size_t)blockIdx.x * NKEYS;

  uint4 z4 = {0, 0, 0, 0};
  #pragma unroll
  for (int i = 0; i < 4; ++i) ((uint4*)hist)[tid + 256 * i] = z4;
  if (tid == 0) { cntA = 0; cntC = 0; }

  uint32_t key[16];
  const int base = (w << 10) + (lane << 4);
  {
    const float4* p4 = (const float4*)(srow + base);
    #pragma unroll
    for (int i = 0; i < 4; ++i) {
      float4 t = p4[i];
      float tv[4] = { t.x, t.y, t.z, t.w };
      #pragma unroll
      for (int c = 0; c < 4; ++c) {
        uint32_t u = __float_as_uint(tv[c]);
        key[i * 4 + c] = u ^ (uint32_t)(((int32_t)u >> 31) | 0x80000000);
      }
    }
  }
  __syncthreads();

  #pragma unroll
  for (int j = 0; j < 16; ++j) atomicAdd(&hist[key[j] >> 20], 1u);
  __syncthreads();

  uint32_t h[16];
  #pragma unroll
  for (int i = 0; i < 16; ++i) h[i] = hist[tid * 16 + i];
  uint32_t sfx[17]; sfx[16] = 0;
  #pragma unroll
  for (int i = 15; i >= 0; --i) sfx[i] = sfx[i + 1] + h[i];
  sA[tid] = sfx[0];
  __syncthreads();
  uint32_t s = sfx[0];
  #pragma unroll
  for (int off = 1; off < 256; off <<= 1) {
    uint32_t add = (tid + off < 256) ? sA[tid + off] : 0;
    __syncthreads();
    s += add; sA[tid] = s;
    __syncthreads();
  }
  const uint32_t exclHi = s - sfx[0];

  #pragma unroll
  for (int i = 0; i < 16; ++i) {
    uint32_t cg = exclHi + sfx[i + 1];
    if (cg < KTOP && cg + h[i] >= KTOP) { s_p = tid * 16 + i; s_above = cg; }
  }
  __syncthreads();
  const uint32_t p = (uint32_t)s_p;
  const uint32_t above = s_above;
  const uint32_t need = KTOP - above;

  uint32_t* ck = hist;
  uint32_t* ci = hist + 2048;
  #pragma unroll
  for (int j = 0; j < 16; ++j) {
    uint32_t b = key[j] >> 20;
    if (b >= p) {
      uint32_t idx = (uint32_t)(base + j);
      if (b > p) { uint32_t pos = atomicAdd(&cntA, 1u); av[pos] = key[j]; ai[pos] = idx; }
      else       { uint32_t pos = atomicAdd(&cntC, 1u); if (pos < 2048u) { ck[pos] = key[j]; ci[pos] = idx; } }
    }
  }
  __syncthreads();

  const uint32_t nA = cntA;
  if (tid < nA) { sk[tid] = av[tid]; si[tid] = ai[tid]; }

  if (w == 0) {
    const uint32_t nC = min(cntC, 2048u);
    for (uint32_t k = 0; k < need; ++k) {
      uint32_t bk = 0, bi = 0xFFFFFFFFu, bp = 0;
      for (uint32_t c = lane; c < nC; c += 64) {
        uint32_t kk = ck[c], ii = ci[c];
        if (kk > bk || (kk == bk && ii < bi)) { bk = kk; bi = ii; bp = c; }
      }
      #pragma unroll
      for (int off = 32; off >= 1; off >>= 1) {
        uint32_t ok = __shfl_down(bk, off);
        uint32_t oi = __shfl_down(bi, off);
        uint32_t op = __shfl_down(bp, off);
        if (ok > bk || (ok == bk && oi < bi)) { bk = ok; bi = oi; bp = op; }
      }
      bp = __shfl(bp, 0);
      if (lane == 0) { ck[bp] = 0; sk[nA + k] = bk; si[nA + k] = bi; }
    }
  }
  __syncthreads();

  if (tid == 0) {
    float f[KTOP]; float mx = 0.f;
    #pragma unroll
    for (int k = 0; k < KTOP; ++k) {
      uint32_t kk = sk[k];
      float fv = (kk & 0x80000000u) ? __uint_as_float(kk ^ 0x80000000u)
                                    : __uint_as_float(~kk);
      f[k] = fv; mx = fmaxf(mx, fv);
    }
    float eo = __expf(-mx);
    float Z = (float)(NKEYS - KTOP) * eo;
    float e[KTOP];
    #pragma unroll
    for (int k = 0; k < KTOP; ++k) { e[k] = __expf(f[k] - mx); Z += e[k]; }
    float inv = 1.f / Z;
    #pragma unroll
    for (int k = 0; k < KTOP; ++k) gk[k] = e[k] * inv;
    s_gother = eo * inv;
  }
  __syncthreads();

  float go = s_gother;
  float4 g4 = { go, go, go, go };
  float* grow = gates + (size_t)blockIdx.x * NKEYS;
  #pragma unroll
  for (int j = 0; j < 4; ++j) ((float4*)grow)[j * 256 + tid] = g4;
  __syncthreads();
  if (tid < KTOP) grow[si[tid]] = gk[tid];
}

extern "C" void kernel_launch(void* const* d_in, const int* in_sizes, int n_in,
                              void* d_out, int out_size, void* d_ws, size_t ws_size,
                              hipStream_t stream) {
  const float* x    = (const float*)d_in[0];
  const float* keys = (const float*)d_in[1];
  const float* W    = (const float*)d_in[2];
  const float* bias = (const float*)d_in[3];
  (void)in_sizes; (void)n_in; (void)out_size; (void)ws_size;

  float* gates  = (float*)d_out;
  float* scores = (float*)d_out + (size_t)BS_T * NKEYS;

  _Float16* W_h = (_Float16*)d_ws;                 // 4 MB
  _Float16* k_h = W_h + (size_t)KDIM * XDIM;       // 4 MB
  _Float16* q_h = k_h + (size_t)NKEYS * KDIM;      // 16 MB

  cvt_f32_f16_v<<<dim3(1024), dim3(256), 0, stream>>>(W, W_h, KDIM * XDIM / 8);
  cvt_f32_f16_v<<<dim3(1024), dim3(256), 0, stream>>>(keys, k_h, NKEYS * KDIM / 8);

  // query = x @ W^T + b -> q_h (fp16). BM=64/BN=256, 2 blocks/CU, grid 512
  gemm1_fused<<<dim3((BS_T / 64) * 2), dim3(256), 0, stream>>>(x, W_h, bias, q_h);

  // scores = q @ keys^T -> fp32. 256x256 tiles, counted-vmcnt pipeline, grid 1024
  gemm2_pipe<<<dim3((BS_T / 256) * (NKEYS / 256)), dim3(512), 0, stream>>>(
      q_h, k_h, scores);

  topk_gates_kernel<<<dim3(BS_T), dim3(256), 0, stream>>>(scores, gates);
}

// Round 10
// 351.763 us; speedup vs baseline: 2.0288x; 1.0230x over previous
//
#include <hip/hip_runtime.h>
#include <stdint.h>

#define BS_T   16384
#define XDIM   4096
#define KDIM   512
#define NKEYS  4096
#define KTOP   16

typedef _Float16 half8  __attribute__((ext_vector_type(8)));
typedef float    floatx4 __attribute__((ext_vector_type(4)));

// async global->LDS, 16B per lane; LDS dest is wave-uniform base + lane*16
__device__ static inline void gload_lds16(const void* g, void* l) {
  __builtin_amdgcn_global_load_lds(
      (const __attribute__((address_space(1))) uint32_t*)(uintptr_t)g,
      (__attribute__((address_space(3))) uint32_t*)(uint32_t)(uintptr_t)l,
      16, 0, 0);
}

#define FULL_BAR() do { __builtin_amdgcn_sched_barrier(0); \
                        __builtin_amdgcn_s_barrier(); \
                        __builtin_amdgcn_sched_barrier(0); } while (0)

// ---------------- fp32 -> fp16 convert (vectorized, grid-stride) ----------------
__global__ __launch_bounds__(256) void cvt_f32_f16_v(const float* __restrict__ in,
                                                     _Float16* __restrict__ out, int n8) {
  int stride = gridDim.x * 256;
  for (int i = blockIdx.x * 256 + threadIdx.x; i < n8; i += stride) {
    float4 v0 = ((const float4*)in)[2 * i];
    float4 v1 = ((const float4*)in)[2 * i + 1];
    half8 h = { (_Float16)v0.x, (_Float16)v0.y, (_Float16)v0.z, (_Float16)v0.w,
                (_Float16)v1.x, (_Float16)v1.y, (_Float16)v1.z, (_Float16)v1.w };
    ((half8*)out)[i] = h;
  }
}

// ---------------- GEMM1 pipelined: Q[M,512] = cvt16(X[M,4096]) @ W16^T + b --------
// BM=64, BN=512 (full N -> x read exactly ONCE = 256 MB). 8 waves, wave w owns cols
// w*64.. Counted-vmcnt 2-phase schedule (same discipline as gemm2_pipe, R9-verified):
// P1 {16 frag ds_reads + issue A(t+2) fp32->regs; bar; lgkm0; 16 MFMA; bar}
// P2 {stage B(t+2) gload_lds (region's readers drained P1); ds_write A(t+1) to the
//     non-current buffer; lgkm0; 16 MFMA; vmcnt(10) gate; bar}
// vmcnt(10) drains B(t+1) only -- A(t+2)[2]+B(t+2)[8] stay in flight across barriers.
__global__ __launch_bounds__(512, 1)
void gemm1_pipe(const float* __restrict__ X, const _Float16* __restrict__ Wh,
                const float* __restrict__ bias, _Float16* __restrict__ Q) {
  __shared__ __align__(16) _Float16 ldsA[2][64 * 64];    // 2 x 8 KB
  __shared__ __align__(16) _Float16 ldsB[2][512 * 64];   // 2 x 64 KB

  const int tid  = threadIdx.x;
  const int lane = tid & 63;
  const int wid  = tid >> 6;            // 0..7
  const int rowBase = blockIdx.x * 64;
  const int wc  = wid * 64;
  const int l15 = lane & 15;
  const int q4  = lane >> 4;
  const int sub   = lane >> 3;
  const int gslot = (lane & 7) ^ sub;

  // A reg-staging: thread -> (row=tid>>3, 8-fp32 slot=tid&7), coalesced 256B rows
  const int arow  = tid >> 3;
  const int aslot = tid & 7;
  const float* aSrcT = X + (size_t)(rowBase + arow) * XDIM + aslot * 8;
  const int aoff = arow * 128 + ((aslot * 16) ^ ((arow & 7) << 4));
  // B staging: wave w stages its own rows wc..wc+63 (groups wid*8..wid*8+7)
  const _Float16* const bSrc = Wh + (size_t)(wc + sub) * XDIM + gslot * 8;

  auto stageB = [&](int kt, int buf) {
    char* bd = (char*)&ldsB[buf][0] + wid * 8192;
    #pragma unroll
    for (int i = 0; i < 8; ++i)
      gload_lds16(bSrc + (size_t)i * 8 * XDIM + kt, bd + i * 1024);
  };
  auto writeA = [&](int buf, float4 v0, float4 v1) {
    half8 h = { (_Float16)v0.x, (_Float16)v0.y, (_Float16)v0.z, (_Float16)v0.w,
                (_Float16)v1.x, (_Float16)v1.y, (_Float16)v1.z, (_Float16)v1.w };
    *(half8*)((char*)&ldsA[buf][0] + aoff) = h;
  };
  auto ld8 = [&](const char* base, int row, int s) {
    return *(const half8*)(base + row * 128 + ((s * 16) ^ ((row & 7) << 4)));
  };

  floatx4 acc[4][4];
  #pragma unroll
  for (int m = 0; m < 4; ++m)
    #pragma unroll
    for (int n = 0; n < 4; ++n)
      acc[m][n] = (floatx4)0.0f;

  // ---- prologue: A(0)->LDS, A(1)->regs, B(0)+B(1) staged ----
  float4 p00 = *(const float4*)(aSrcT);
  float4 p01 = *(const float4*)(aSrcT + 4);
  float4 aw0 = *(const float4*)(aSrcT + 64);
  float4 aw1 = *(const float4*)(aSrcT + 68);
  stageB(0, 0);
  stageB(64, 1);
  writeA(0, p00, p01);                                  // compiler waits A(0) loads
  asm volatile("s_waitcnt vmcnt(8)" ::: "memory");      // A(1)+B(0) drained; B(1) flies
  asm volatile("s_waitcnt lgkmcnt(0)" ::: "memory");
  __builtin_amdgcn_sched_barrier(0);
  __builtin_amdgcn_s_barrier();
  __builtin_amdgcn_sched_barrier(0);

  for (int t = 0; t < 64; ++t) {
    const int cu = t & 1;
    const char* bA = (const char*)&ldsA[cu][0];
    const char* bB = (const char*)&ldsB[cu][0];
    half8 a[4][2], b[4][2];

    // ---- P1: all frag reads + A(t+2) global->reg; MFMA n=0,1 ----
    #pragma unroll
    for (int m = 0; m < 4; ++m)
      #pragma unroll
      for (int kk = 0; kk < 2; ++kk)
        a[m][kk] = ld8(bA, m * 16 + l15, kk * 4 + q4);
    #pragma unroll
    for (int n = 0; n < 4; ++n)
      #pragma unroll
      for (int kk = 0; kk < 2; ++kk)
        b[n][kk] = ld8(bB, wc + n * 16 + l15, kk * 4 + q4);
    float4 nl0, nl1;
    if (t < 62) {
      nl0 = *(const float4*)(aSrcT + (t + 2) * 64);
      nl1 = *(const float4*)(aSrcT + (t + 2) * 64 + 4);
    }
    FULL_BAR();
    asm volatile("s_waitcnt lgkmcnt(0)" ::: "memory");
    __builtin_amdgcn_sched_barrier(0);
    __builtin_amdgcn_s_setprio(1);
    #pragma unroll
    for (int m = 0; m < 4; ++m)
      #pragma unroll
      for (int n = 0; n < 2; ++n)
        #pragma unroll
        for (int kk = 0; kk < 2; ++kk)
          acc[m][n] = __builtin_amdgcn_mfma_f32_16x16x32_f16(a[m][kk], b[n][kk], acc[m][n], 0, 0, 0);
    __builtin_amdgcn_s_setprio(0);
    FULL_BAR();

    // ---- P2: stage B(t+2); ds_write A(t+1); MFMA n=2,3; vmcnt gate ----
    if (t < 62) stageB((t + 2) * 64, cu);
    if (t < 63) writeA(cu ^ 1, aw0, aw1);               // compiler waits A(t+1) loads
    asm volatile("s_waitcnt lgkmcnt(0)" ::: "memory");  // drain the ds_write
    __builtin_amdgcn_sched_barrier(0);
    __builtin_amdgcn_s_setprio(1);
    #pragma unroll
    for (int m = 0; m < 4; ++m)
      #pragma unroll
      for (int n = 2; n < 4; ++n)
        #pragma unroll
        for (int kk = 0; kk < 2; ++kk)
          acc[m][n] = __builtin_amdgcn_mfma_f32_16x16x32_f16(a[m][kk], b[n][kk], acc[m][n], 0, 0, 0);
    __builtin_amdgcn_s_setprio(0);
    __builtin_amdgcn_sched_barrier(0);
    if (t < 62)       asm volatile("s_waitcnt vmcnt(10)" ::: "memory");
    else if (t == 62) asm volatile("s_waitcnt vmcnt(0)"  ::: "memory");
    FULL_BAR();
    aw0 = nl0; aw1 = nl1;
  }

  // epilogue: C/D layout col=lane&15, row=(lane>>4)*4+r; fused bias + fp16 store
  #pragma unroll
  for (int m = 0; m < 4; ++m) {
    #pragma unroll
    for (int n = 0; n < 4; ++n) {
      int col = wc + n * 16 + l15;
      float bv = bias[col];
      #pragma unroll
      for (int r = 0; r < 4; ++r) {
        int row = rowBase + m * 16 + q4 * 4 + r;
        Q[(size_t)row * KDIM + col] = (_Float16)(acc[m][n][r] + bv);
      }
    }
  }
}

// ---------------- GEMM2 pipelined (unchanged from R9) ----------------
__global__ __launch_bounds__(512, 2)
void gemm2_pipe(const _Float16* __restrict__ Aq, const _Float16* __restrict__ Bk,
                float* __restrict__ outp) {
  __shared__ __align__(16) _Float16 ldsA[2][256 * 64];
  __shared__ __align__(16) _Float16 ldsB[2][256 * 64];

  const int tid  = threadIdx.x;
  const int lane = tid & 63;
  const int wid  = tid >> 6;
  const int cpx  = gridDim.x >> 3;
  const int bid  = (blockIdx.x & 7) * cpx + (blockIdx.x >> 3);
  const int nCol = NKEYS / 256;
  const int rowBase = (bid / nCol) * 256;
  const int colBase = (bid % nCol) * 256;
  const int wm = wid >> 2;
  const int wn = wid & 3;
  const int l15 = lane & 15;
  const int q4  = lane >> 4;
  const int sub   = lane >> 3;
  const int gslot = (lane & 7) ^ sub;

  const _Float16* aSrc = Aq + (size_t)rowBase * KDIM;
  const _Float16* bSrc = Bk + (size_t)colBase * KDIM;

  auto stageHalf = [&](const _Float16* src, char* ldsbase, int kt, int h) {
    #pragma unroll
    for (int j = 0; j < 2; ++j) {
      int g = h * 16 + wid * 2 + j;
      gload_lds16(src + (size_t)(g * 8 + sub) * KDIM + kt + gslot * 8,
                  ldsbase + g * 1024);
    }
  };
  auto ld8 = [&](const char* base, int row, int s) {
    return *(const half8*)(base + row * 128 + ((s * 16) ^ ((row & 7) << 4)));
  };

  floatx4 acc[8][4];
  #pragma unroll
  for (int m = 0; m < 8; ++m)
    #pragma unroll
    for (int n = 0; n < 4; ++n)
      acc[m][n] = (floatx4)0.0f;

  stageHalf(aSrc, (char*)ldsA[0], 0, 0);
  stageHalf(aSrc, (char*)ldsA[0], 0, 1);
  stageHalf(bSrc, (char*)ldsB[0], 0, 0);
  stageHalf(bSrc, (char*)ldsB[0], 0, 1);
  stageHalf(aSrc, (char*)ldsA[1], 64, 0);
  stageHalf(aSrc, (char*)ldsA[1], 64, 1);
  stageHalf(bSrc, (char*)ldsB[1], 64, 0);
  stageHalf(bSrc, (char*)ldsB[1], 64, 1);
  asm volatile("s_waitcnt vmcnt(8)" ::: "memory");
  FULL_BAR();

  for (int t = 0; t < 8; ++t) {
    const char* bA = (const char*)ldsA[t & 1];
    const char* bB = (const char*)ldsB[t & 1];
    char* sA = (char*)ldsA[t & 1];
    char* sB = (char*)ldsB[t & 1];
    const int ktn = (t + 2) * 64;
    const bool st = (t < 6);

    half8 a[4][2], b[4][2];

    #pragma unroll
    for (int m = 0; m < 4; ++m)
      #pragma unroll
      for (int kk = 0; kk < 2; ++kk)
        a[m][kk] = ld8(bA, wm * 128 + m * 16 + l15, kk * 4 + q4);
    #pragma unroll
    for (int n = 0; n < 4; ++n)
      #pragma unroll
      for (int kk = 0; kk < 2; ++kk)
        b[n][kk] = ld8(bB, wn * 64 + n * 16 + l15, kk * 4 + q4);
    FULL_BAR();
    asm volatile("s_waitcnt lgkmcnt(0)" ::: "memory");
    __builtin_amdgcn_sched_barrier(0);
    __builtin_amdgcn_s_setprio(1);
    #pragma unroll
    for (int m = 0; m < 4; ++m)
      #pragma unroll
      for (int n = 0; n < 2; ++n)
        #pragma unroll
        for (int kk = 0; kk < 2; ++kk)
          acc[m][n] = __builtin_amdgcn_mfma_f32_16x16x32_f16(a[m][kk], b[n][kk], acc[m][n], 0, 0, 0);
    __builtin_amdgcn_s_setprio(0);
    FULL_BAR();

    if (st) stageHalf(bSrc, sB, ktn, 0);
    __builtin_amdgcn_sched_barrier(0);
    __builtin_amdgcn_s_setprio(1);
    #pragma unroll
    for (int m = 0; m < 4; ++m)
      #pragma unroll
      for (int n = 2; n < 4; ++n)
        #pragma unroll
        for (int kk = 0; kk < 2; ++kk)
          acc[m][n] = __builtin_amdgcn_mfma_f32_16x16x32_f16(a[m][kk], b[n][kk], acc[m][n], 0, 0, 0);
    __builtin_amdgcn_s_setprio(0);
    FULL_BAR();

    #pragma unroll
    for (int m = 0; m < 4; ++m)
      #pragma unroll
      for (int kk = 0; kk < 2; ++kk)
        a[m][kk] = ld8(bA, wm * 128 + (m + 4) * 16 + l15, kk * 4 + q4);
    if (st) stageHalf(bSrc, sB, ktn, 1);
    FULL_BAR();
    asm volatile("s_waitcnt lgkmcnt(0)" ::: "memory");
    __builtin_amdgcn_sched_barrier(0);
    __builtin_amdgcn_s_setprio(1);
    #pragma unroll
    for (int m = 0; m < 4; ++m)
      #pragma unroll
      for (int n = 0; n < 2; ++n)
        #pragma unroll
        for (int kk = 0; kk < 2; ++kk)
          acc[m + 4][n] = __builtin_amdgcn_mfma_f32_16x16x32_f16(a[m][kk], b[n][kk], acc[m + 4][n], 0, 0, 0);
    __builtin_amdgcn_s_setprio(0);
    FULL_BAR();

    if (st) { stageHalf(aSrc, sA, ktn, 0); stageHalf(aSrc, sA, ktn, 1); }
    __builtin_amdgcn_sched_barrier(0);
    __builtin_amdgcn_s_setprio(1);
    #pragma unroll
    for (int m = 0; m < 4; ++m)
      #pragma unroll
      for (int n = 2; n < 4; ++n)
        #pragma unroll
        for (int kk = 0; kk < 2; ++kk)
          acc[m + 4][n] = __builtin_amdgcn_mfma_f32_16x16x32_f16(a[m][kk], b[n][kk], acc[m + 4][n], 0, 0, 0);
    __builtin_amdgcn_s_setprio(0);
    __builtin_amdgcn_sched_barrier(0);
    if (t < 6)      asm volatile("s_waitcnt vmcnt(8)" ::: "memory");
    else if (t == 6) asm volatile("s_waitcnt vmcnt(0)" ::: "memory");
    FULL_BAR();
  }

  #pragma unroll
  for (int m = 0; m < 8; ++m) {
    #pragma unroll
    for (int n = 0; n < 4; ++n) {
      int col = colBase + wn * 64 + n * 16 + l15;
      #pragma unroll
      for (int r = 0; r < 4; ++r) {
        int row = rowBase + wm * 128 + m * 16 + q4 * 4 + r;
        outp[(size_t)row * NKEYS + col] = acc[m][n][r];
      }
    }
  }
}

// ---------------- top-16 + scatter-softmax gates (radix-select) ----------------
__global__ __launch_bounds__(256) void topk_gates_kernel(const float* __restrict__ scores,
                                                         float* __restrict__ gates) {
  __shared__ uint32_t hist[4096];
  __shared__ uint32_t sA[256];
  __shared__ uint32_t av[16], ai[16];
  __shared__ uint32_t sk[KTOP], si[KTOP];
  __shared__ uint32_t cntA, cntC;
  __shared__ int s_p; __shared__ uint32_t s_above;
  __shared__ float gk[KTOP]; __shared__ float s_gother;

  const int tid  = threadIdx.x;
  const int lane = tid & 63;
  const int w    = tid >> 6;
  const float* srow = scores + (size_t)blockIdx.x * NKEYS;

  uint4 z4 = {0, 0, 0, 0};
  #pragma unroll
  for (int i = 0; i < 4; ++i) ((uint4*)hist)[tid + 256 * i] = z4;
  if (tid == 0) { cntA = 0; cntC = 0; }

  uint32_t key[16];
  const int base = (w << 10) + (lane << 4);
  {
    const float4* p4 = (const float4*)(srow + base);
    #pragma unroll
    for (int i = 0; i < 4; ++i) {
      float4 t = p4[i];
      float tv[4] = { t.x, t.y, t.z, t.w };
      #pragma unroll
      for (int c = 0; c < 4; ++c) {
        uint32_t u = __float_as_uint(tv[c]);
        key[i * 4 + c] = u ^ (uint32_t)(((int32_t)u >> 31) | 0x80000000);
      }
    }
  }
  __syncthreads();

  #pragma unroll
  for (int j = 0; j < 16; ++j) atomicAdd(&hist[key[j] >> 20], 1u);
  __syncthreads();

  uint32_t h[16];
  #pragma unroll
  for (int i = 0; i < 16; ++i) h[i] = hist[tid * 16 + i];
  uint32_t sfx[17]; sfx[16] = 0;
  #pragma unroll
  for (int i = 15; i >= 0; --i) sfx[i] = sfx[i + 1] + h[i];
  sA[tid] = sfx[0];
  __syncthreads();
  uint32_t s = sfx[0];
  #pragma unroll
  for (int off = 1; off < 256; off <<= 1) {
    uint32_t add = (tid + off < 256) ? sA[tid + off] : 0;
    __syncthreads();
    s += add; sA[tid] = s;
    __syncthreads();
  }
  const uint32_t exclHi = s - sfx[0];

  #pragma unroll
  for (int i = 0; i < 16; ++i) {
    uint32_t cg = exclHi + sfx[i + 1];
    if (cg < KTOP && cg + h[i] >= KTOP) { s_p = tid * 16 + i; s_above = cg; }
  }
  __syncthreads();
  const uint32_t p = (uint32_t)s_p;
  const uint32_t above = s_above;
  const uint32_t need = KTOP - above;

  uint32_t* ck = hist;
  uint32_t* ci = hist + 2048;
  #pragma unroll
  for (int j = 0; j < 16; ++j) {
    uint32_t b = key[j] >> 20;
    if (b >= p) {
      uint32_t idx = (uint32_t)(base + j);
      if (b > p) { uint32_t pos = atomicAdd(&cntA, 1u); av[pos] = key[j]; ai[pos] = idx; }
      else       { uint32_t pos = atomicAdd(&cntC, 1u); if (pos < 2048u) { ck[pos] = key[j]; ci[pos] = idx; } }
    }
  }
  __syncthreads();

  const uint32_t nA = cntA;
  if (tid < nA) { sk[tid] = av[tid]; si[tid] = ai[tid]; }

  if (w == 0) {
    const uint32_t nC = min(cntC, 2048u);
    for (uint32_t k = 0; k < need; ++k) {
      uint32_t bk = 0, bi = 0xFFFFFFFFu, bp = 0;
      for (uint32_t c = lane; c < nC; c += 64) {
        uint32_t kk = ck[c], ii = ci[c];
        if (kk > bk || (kk == bk && ii < bi)) { bk = kk; bi = ii; bp = c; }
      }
      #pragma unroll
      for (int off = 32; off >= 1; off >>= 1) {
        uint32_t ok = __shfl_down(bk, off);
        uint32_t oi = __shfl_down(bi, off);
        uint32_t op = __shfl_down(bp, off);
        if (ok > bk || (ok == bk && oi < bi)) { bk = ok; bi = oi; bp = op; }
      }
      bp = __shfl(bp, 0);
      if (lane == 0) { ck[bp] = 0; sk[nA + k] = bk; si[nA + k] = bi; }
    }
  }
  __syncthreads();

  if (tid == 0) {
    float f[KTOP]; float mx = 0.f;
    #pragma unroll
    for (int k = 0; k < KTOP; ++k) {
      uint32_t kk = sk[k];
      float fv = (kk & 0x80000000u) ? __uint_as_float(kk ^ 0x80000000u)
                                    : __uint_as_float(~kk);
      f[k] = fv; mx = fmaxf(mx, fv);
    }
    float eo = __expf(-mx);
    float Z = (float)(NKEYS - KTOP) * eo;
    float e[KTOP];
    #pragma unroll
    for (int k = 0; k < KTOP; ++k) { e[k] = __expf(f[k] - mx); Z += e[k]; }
    float inv = 1.f / Z;
    #pragma unroll
    for (int k = 0; k < KTOP; ++k) gk[k] = e[k] * inv;
    s_gother = eo * inv;
  }
  __syncthreads();

  float go = s_gother;
  float4 g4 = { go, go, go, go };
  float* grow = gates + (size_t)blockIdx.x * NKEYS;
  #pragma unroll
  for (int j = 0; j < 4; ++j) ((float4*)grow)[j * 256 + tid] = g4;
  __syncthreads();
  if (tid < KTOP) grow[si[tid]] = gk[tid];
}

extern "C" void kernel_launch(void* const* d_in, const int* in_sizes, int n_in,
                              void* d_out, int out_size, void* d_ws, size_t ws_size,
                              hipStream_t stream) {
  const float* x    = (const float*)d_in[0];
  const float* keys = (const float*)d_in[1];
  const float* W    = (const float*)d_in[2];
  const float* bias = (const float*)d_in[3];
  (void)in_sizes; (void)n_in; (void)out_size; (void)ws_size;

  float* gates  = (float*)d_out;
  float* scores = (float*)d_out + (size_t)BS_T * NKEYS;

  _Float16* W_h = (_Float16*)d_ws;                 // 4 MB
  _Float16* k_h = W_h + (size_t)KDIM * XDIM;       // 4 MB
  _Float16* q_h = k_h + (size_t)NKEYS * KDIM;      // 16 MB

  cvt_f32_f16_v<<<dim3(1024), dim3(256), 0, stream>>>(W, W_h, KDIM * XDIM / 8);
  cvt_f32_f16_v<<<dim3(1024), dim3(256), 0, stream>>>(keys, k_h, NKEYS * KDIM / 8);

  // query = x @ W^T + b -> q_h (fp16). x read ONCE; counted-vmcnt pipeline, grid 256
  gemm1_pipe<<<dim3(BS_T / 64), dim3(512), 0, stream>>>(x, W_h, bias, q_h);

  // scores = q @ keys^T -> fp32. 256x256 tiles, counted-vmcnt pipeline, grid 1024
  gemm2_pipe<<<dim3((BS_T / 256) * (NKEYS / 256)), dim3(512), 0, stream>>>(
      q_h, k_h, scores);

  topk_gates_kernel<<<dim3(BS_T), dim3(256), 0, stream>>>(scores, gates);
}

// Round 11
// 344.902 us; speedup vs baseline: 2.0691x; 1.0199x over previous
//
#include <hip/hip_runtime.h>
#include <stdint.h>

#define BS_T   16384
#define XDIM   4096
#define KDIM   512
#define NKEYS  4096
#define KTOP   16

typedef _Float16 half8  __attribute__((ext_vector_type(8)));
typedef float    floatx4 __attribute__((ext_vector_type(4)));

// async global->LDS, 16B per lane; LDS dest is wave-uniform base + lane*16
__device__ static inline void gload_lds16(const void* g, void* l) {
  __builtin_amdgcn_global_load_lds(
      (const __attribute__((address_space(1))) uint32_t*)(uintptr_t)g,
      (__attribute__((address_space(3))) uint32_t*)(uint32_t)(uintptr_t)l,
      16, 0, 0);
}

#define FULL_BAR() do { __builtin_amdgcn_sched_barrier(0); \
                        __builtin_amdgcn_s_barrier(); \
                        __builtin_amdgcn_sched_barrier(0); } while (0)

// ---------------- fp32 -> fp16 convert (vectorized, grid-stride) ----------------
__global__ __launch_bounds__(256) void cvt_f32_f16_v(const float* __restrict__ in,
                                                     _Float16* __restrict__ out, int n8) {
  int stride = gridDim.x * 256;
  for (int i = blockIdx.x * 256 + threadIdx.x; i < n8; i += stride) {
    float4 v0 = ((const float4*)in)[2 * i];
    float4 v1 = ((const float4*)in)[2 * i + 1];
    half8 h = { (_Float16)v0.x, (_Float16)v0.y, (_Float16)v0.z, (_Float16)v0.w,
                (_Float16)v1.x, (_Float16)v1.y, (_Float16)v1.z, (_Float16)v1.w };
    ((half8*)out)[i] = h;
  }
}

// ---------------- GEMM1 v6: Q[M,512] = cvt16(X[M,4096]) @ W16^T + b ---------------
// BM=64, BN=512 (x read exactly ONCE). 8 waves; wave w's B slice (rows wc..wc+63)
// is WAVE-PRIVATE (stages it, reads it) -> B needs no barrier, only own-wave
// counted vmcnt. Only the shared 8KB A tile needs cross-wave ordering ->
// ONE barrier per K-tile, 32 contiguous MFMA per tile:
//   reads A(t)+B(t) -> lgkm0 (retired) -> stageB(t+2) same buf + loadA(t+2)->regs
//   -> 32 MFMA -> writeA(t+1) other buf -> lgkm0 -> vmcnt(10) -> s_barrier
// vmcnt(10) drains B(t+1) (oldest 8), leaves A(t+2)2+B(t+2)8 in flight.
__global__ __launch_bounds__(512, 1)
void gemm1_pipe(const float* __restrict__ X, const _Float16* __restrict__ Wh,
                const float* __restrict__ bias, _Float16* __restrict__ Q) {
  __shared__ __align__(16) _Float16 ldsA[2][64 * 64];    // 2 x 8 KB
  __shared__ __align__(16) _Float16 ldsB[2][512 * 64];   // 2 x 64 KB

  const int tid  = threadIdx.x;
  const int lane = tid & 63;
  const int wid  = tid >> 6;            // 0..7
  const int rowBase = blockIdx.x * 64;
  const int wc  = wid * 64;
  const int l15 = lane & 15;
  const int q4  = lane >> 4;
  const int sub   = lane >> 3;
  const int gslot = (lane & 7) ^ sub;

  const int arow  = tid >> 3;
  const int aslot = tid & 7;
  const float* aSrcT = X + (size_t)(rowBase + arow) * XDIM + aslot * 8;
  const int aoff = arow * 128 + ((aslot * 16) ^ ((arow & 7) << 4));
  const _Float16* const bSrc = Wh + (size_t)(wc + sub) * XDIM + gslot * 8;

  auto stageB = [&](int kt, int buf) {
    char* bd = (char*)&ldsB[buf][0] + wid * 8192;
    #pragma unroll
    for (int i = 0; i < 8; ++i)
      gload_lds16(bSrc + (size_t)i * 8 * XDIM + kt, bd + i * 1024);
  };
  auto writeA = [&](int buf, float4 v0, float4 v1) {
    half8 h = { (_Float16)v0.x, (_Float16)v0.y, (_Float16)v0.z, (_Float16)v0.w,
                (_Float16)v1.x, (_Float16)v1.y, (_Float16)v1.z, (_Float16)v1.w };
    *(half8*)((char*)&ldsA[buf][0] + aoff) = h;
  };
  auto ld8 = [&](const char* base, int row, int s) {
    return *(const half8*)(base + row * 128 + ((s * 16) ^ ((row & 7) << 4)));
  };

  floatx4 acc[4][4];
  #pragma unroll
  for (int m = 0; m < 4; ++m)
    #pragma unroll
    for (int n = 0; n < 4; ++n)
      acc[m][n] = (floatx4)0.0f;

  // ---- prologue ----
  float4 p0  = *(const float4*)(aSrcT);
  float4 p1  = *(const float4*)(aSrcT + 4);
  float4 aw0 = *(const float4*)(aSrcT + 64);
  float4 aw1 = *(const float4*)(aSrcT + 68);
  stageB(0, 0);
  stageB(64, 1);
  writeA(0, p0, p1);                                    // compiler waits p loads
  asm volatile("s_waitcnt lgkmcnt(0)" ::: "memory");
  asm volatile("s_waitcnt vmcnt(8)" ::: "memory");      // drain aw + B(0); B(1) flies
  FULL_BAR();

  #pragma unroll 2
  for (int t = 0; t < 64; ++t) {
    const int cu = t & 1;
    const char* bA = (const char*)&ldsA[cu][0];
    const char* bB = (const char*)&ldsB[cu][0];

    // frag reads (A shared tile + own B slice)
    half8 a[4][2], b[4][2];
    #pragma unroll
    for (int m = 0; m < 4; ++m)
      #pragma unroll
      for (int kk = 0; kk < 2; ++kk)
        a[m][kk] = ld8(bA, m * 16 + l15, kk * 4 + q4);
    #pragma unroll
    for (int n = 0; n < 4; ++n)
      #pragma unroll
      for (int kk = 0; kk < 2; ++kk)
        b[n][kk] = ld8(bB, wc + n * 16 + l15, kk * 4 + q4);
    // A(t+2) -> regs (consumed by writeA next tile)
    float4 nl0, nl1;
    if (t < 62) {
      nl0 = *(const float4*)(aSrcT + (t + 2) * 64);
      nl1 = *(const float4*)(aSrcT + (t + 2) * 64 + 4);
    }
    // retire frag reads, then overwrite own B slice (wave-private -> race-free)
    asm volatile("s_waitcnt lgkmcnt(0)" ::: "memory");
    __builtin_amdgcn_sched_barrier(0);
    if (t < 62) stageB((t + 2) * 64, cu);
    __builtin_amdgcn_sched_barrier(0);

    __builtin_amdgcn_s_setprio(1);
    #pragma unroll
    for (int m = 0; m < 4; ++m)
      #pragma unroll
      for (int n = 0; n < 4; ++n)
        #pragma unroll
        for (int kk = 0; kk < 2; ++kk)
          acc[m][n] = __builtin_amdgcn_mfma_f32_16x16x32_f16(a[m][kk], b[n][kk], acc[m][n], 0, 0, 0);
    __builtin_amdgcn_s_setprio(0);

    if (t < 63) writeA(cu ^ 1, aw0, aw1);               // implicit vmcnt(10), ~free
    asm volatile("s_waitcnt lgkmcnt(0)" ::: "memory");  // A write visible
    __builtin_amdgcn_sched_barrier(0);
    if (t < 62)       asm volatile("s_waitcnt vmcnt(10)" ::: "memory"); // drain B(t+1)
    else if (t == 62) asm volatile("s_waitcnt vmcnt(0)"  ::: "memory");
    FULL_BAR();
    aw0 = nl0; aw1 = nl1;
  }

  // epilogue: C/D layout col=lane&15, row=(lane>>4)*4+r; fused bias + fp16 store
  #pragma unroll
  for (int m = 0; m < 4; ++m) {
    #pragma unroll
    for (int n = 0; n < 4; ++n) {
      int col = wc + n * 16 + l15;
      float bv = bias[col];
      #pragma unroll
      for (int r = 0; r < 4; ++r) {
        int row = rowBase + m * 16 + q4 * 4 + r;
        Q[(size_t)row * KDIM + col] = (_Float16)(acc[m][n][r] + bv);
      }
    }
  }
}

// ---------------- GEMM2 pipelined (unchanged from R9/R10) ----------------
__global__ __launch_bounds__(512, 2)
void gemm2_pipe(const _Float16* __restrict__ Aq, const _Float16* __restrict__ Bk,
                float* __restrict__ outp) {
  __shared__ __align__(16) _Float16 ldsA[2][256 * 64];
  __shared__ __align__(16) _Float16 ldsB[2][256 * 64];

  const int tid  = threadIdx.x;
  const int lane = tid & 63;
  const int wid  = tid >> 6;
  const int cpx  = gridDim.x >> 3;
  const int bid  = (blockIdx.x & 7) * cpx + (blockIdx.x >> 3);
  const int nCol = NKEYS / 256;
  const int rowBase = (bid / nCol) * 256;
  const int colBase = (bid % nCol) * 256;
  const int wm = wid >> 2;
  const int wn = wid & 3;
  const int l15 = lane & 15;
  const int q4  = lane >> 4;
  const int sub   = lane >> 3;
  const int gslot = (lane & 7) ^ sub;

  const _Float16* aSrc = Aq + (size_t)rowBase * KDIM;
  const _Float16* bSrc = Bk + (size_t)colBase * KDIM;

  auto stageHalf = [&](const _Float16* src, char* ldsbase, int kt, int h) {
    #pragma unroll
    for (int j = 0; j < 2; ++j) {
      int g = h * 16 + wid * 2 + j;
      gload_lds16(src + (size_t)(g * 8 + sub) * KDIM + kt + gslot * 8,
                  ldsbase + g * 1024);
    }
  };
  auto ld8 = [&](const char* base, int row, int s) {
    return *(const half8*)(base + row * 128 + ((s * 16) ^ ((row & 7) << 4)));
  };

  floatx4 acc[8][4];
  #pragma unroll
  for (int m = 0; m < 8; ++m)
    #pragma unroll
    for (int n = 0; n < 4; ++n)
      acc[m][n] = (floatx4)0.0f;

  stageHalf(aSrc, (char*)ldsA[0], 0, 0);
  stageHalf(aSrc, (char*)ldsA[0], 0, 1);
  stageHalf(bSrc, (char*)ldsB[0], 0, 0);
  stageHalf(bSrc, (char*)ldsB[0], 0, 1);
  stageHalf(aSrc, (char*)ldsA[1], 64, 0);
  stageHalf(aSrc, (char*)ldsA[1], 64, 1);
  stageHalf(bSrc, (char*)ldsB[1], 64, 0);
  stageHalf(bSrc, (char*)ldsB[1], 64, 1);
  asm volatile("s_waitcnt vmcnt(8)" ::: "memory");
  FULL_BAR();

  for (int t = 0; t < 8; ++t) {
    const char* bA = (const char*)ldsA[t & 1];
    const char* bB = (const char*)ldsB[t & 1];
    char* sA = (char*)ldsA[t & 1];
    char* sB = (char*)ldsB[t & 1];
    const int ktn = (t + 2) * 64;
    const bool st = (t < 6);

    half8 a[4][2], b[4][2];

    #pragma unroll
    for (int m = 0; m < 4; ++m)
      #pragma unroll
      for (int kk = 0; kk < 2; ++kk)
        a[m][kk] = ld8(bA, wm * 128 + m * 16 + l15, kk * 4 + q4);
    #pragma unroll
    for (int n = 0; n < 4; ++n)
      #pragma unroll
      for (int kk = 0; kk < 2; ++kk)
        b[n][kk] = ld8(bB, wn * 64 + n * 16 + l15, kk * 4 + q4);
    FULL_BAR();
    asm volatile("s_waitcnt lgkmcnt(0)" ::: "memory");
    __builtin_amdgcn_sched_barrier(0);
    __builtin_amdgcn_s_setprio(1);
    #pragma unroll
    for (int m = 0; m < 4; ++m)
      #pragma unroll
      for (int n = 0; n < 2; ++n)
        #pragma unroll
        for (int kk = 0; kk < 2; ++kk)
          acc[m][n] = __builtin_amdgcn_mfma_f32_16x16x32_f16(a[m][kk], b[n][kk], acc[m][n], 0, 0, 0);
    __builtin_amdgcn_s_setprio(0);
    FULL_BAR();

    if (st) stageHalf(bSrc, sB, ktn, 0);
    __builtin_amdgcn_sched_barrier(0);
    __builtin_amdgcn_s_setprio(1);
    #pragma unroll
    for (int m = 0; m < 4; ++m)
      #pragma unroll
      for (int n = 2; n < 4; ++n)
        #pragma unroll
        for (int kk = 0; kk < 2; ++kk)
          acc[m][n] = __builtin_amdgcn_mfma_f32_16x16x32_f16(a[m][kk], b[n][kk], acc[m][n], 0, 0, 0);
    __builtin_amdgcn_s_setprio(0);
    FULL_BAR();

    #pragma unroll
    for (int m = 0; m < 4; ++m)
      #pragma unroll
      for (int kk = 0; kk < 2; ++kk)
        a[m][kk] = ld8(bA, wm * 128 + (m + 4) * 16 + l15, kk * 4 + q4);
    if (st) stageHalf(bSrc, sB, ktn, 1);
    FULL_BAR();
    asm volatile("s_waitcnt lgkmcnt(0)" ::: "memory");
    __builtin_amdgcn_sched_barrier(0);
    __builtin_amdgcn_s_setprio(1);
    #pragma unroll
    for (int m = 0; m < 4; ++m)
      #pragma unroll
      for (int n = 0; n < 2; ++n)
        #pragma unroll
        for (int kk = 0; kk < 2; ++kk)
          acc[m + 4][n] = __builtin_amdgcn_mfma_f32_16x16x32_f16(a[m][kk], b[n][kk], acc[m + 4][n], 0, 0, 0);
    __builtin_amdgcn_s_setprio(0);
    FULL_BAR();

    if (st) { stageHalf(aSrc, sA, ktn, 0); stageHalf(aSrc, sA, ktn, 1); }
    __builtin_amdgcn_sched_barrier(0);
    __builtin_amdgcn_s_setprio(1);
    #pragma unroll
    for (int m = 0; m < 4; ++m)
      #pragma unroll
      for (int n = 2; n < 4; ++n)
        #pragma unroll
        for (int kk = 0; kk < 2; ++kk)
          acc[m + 4][n] = __builtin_amdgcn_mfma_f32_16x16x32_f16(a[m][kk], b[n][kk], acc[m + 4][n], 0, 0, 0);
    __builtin_amdgcn_s_setprio(0);
    __builtin_amdgcn_sched_barrier(0);
    if (t < 6)      asm volatile("s_waitcnt vmcnt(8)" ::: "memory");
    else if (t == 6) asm volatile("s_waitcnt vmcnt(0)" ::: "memory");
    FULL_BAR();
  }

  #pragma unroll
  for (int m = 0; m < 8; ++m) {
    #pragma unroll
    for (int n = 0; n < 4; ++n) {
      int col = colBase + wn * 64 + n * 16 + l15;
      #pragma unroll
      for (int r = 0; r < 4; ++r) {
        int row = rowBase + wm * 128 + m * 16 + q4 * 4 + r;
        outp[(size_t)row * NKEYS + col] = acc[m][n][r];
      }
    }
  }
}

// ---------------- top-16 + scatter-softmax gates (radix-select) ----------------
__global__ __launch_bounds__(256) void topk_gates_kernel(const float* __restrict__ scores,
                                                         float* __restrict__ gates) {
  __shared__ uint32_t hist[4096];
  __shared__ uint32_t sA[256];
  __shared__ uint32_t av[16], ai[16];
  __shared__ uint32_t sk[KTOP], si[KTOP];
  __shared__ uint32_t cntA, cntC;
  __shared__ int s_p; __shared__ uint32_t s_above;
  __shared__ float gk[KTOP]; __shared__ float s_gother;

  const int tid  = threadIdx.x;
  const int lane = tid & 63;
  const int w    = tid >> 6;
  const float* srow = scores + (size_t)blockIdx.x * NKEYS;

  uint4 z4 = {0, 0, 0, 0};
  #pragma unroll
  for (int i = 0; i < 4; ++i) ((uint4*)hist)[tid + 256 * i] = z4;
  if (tid == 0) { cntA = 0; cntC = 0; }

  uint32_t key[16];
  const int base = (w << 10) + (lane << 4);
  {
    const float4* p4 = (const float4*)(srow + base);
    #pragma unroll
    for (int i = 0; i < 4; ++i) {
      float4 t = p4[i];
      float tv[4] = { t.x, t.y, t.z, t.w };
      #pragma unroll
      for (int c = 0; c < 4; ++c) {
        uint32_t u = __float_as_uint(tv[c]);
        key[i * 4 + c] = u ^ (uint32_t)(((int32_t)u >> 31) | 0x80000000);
      }
    }
  }
  __syncthreads();

  #pragma unroll
  for (int j = 0; j < 16; ++j) atomicAdd(&hist[key[j] >> 20], 1u);
  __syncthreads();

  uint32_t h[16];
  #pragma unroll
  for (int i = 0; i < 16; ++i) h[i] = hist[tid * 16 + i];
  uint32_t sfx[17]; sfx[16] = 0;
  #pragma unroll
  for (int i = 15; i >= 0; --i) sfx[i] = sfx[i + 1] + h[i];
  sA[tid] = sfx[0];
  __syncthreads();
  uint32_t s = sfx[0];
  #pragma unroll
  for (int off = 1; off < 256; off <<= 1) {
    uint32_t add = (tid + off < 256) ? sA[tid + off] : 0;
    __syncthreads();
    s += add; sA[tid] = s;
    __syncthreads();
  }
  const uint32_t exclHi = s - sfx[0];

  #pragma unroll
  for (int i = 0; i < 16; ++i) {
    uint32_t cg = exclHi + sfx[i + 1];
    if (cg < KTOP && cg + h[i] >= KTOP) { s_p = tid * 16 + i; s_above = cg; }
  }
  __syncthreads();
  const uint32_t p = (uint32_t)s_p;
  const uint32_t above = s_above;
  const uint32_t need = KTOP - above;

  uint32_t* ck = hist;
  uint32_t* ci = hist + 2048;
  #pragma unroll
  for (int j = 0; j < 16; ++j) {
    uint32_t b = key[j] >> 20;
    if (b >= p) {
      uint32_t idx = (uint32_t)(base + j);
      if (b > p) { uint32_t pos = atomicAdd(&cntA, 1u); av[pos] = key[j]; ai[pos] = idx; }
      else       { uint32_t pos = atomicAdd(&cntC, 1u); if (pos < 2048u) { ck[pos] = key[j]; ci[pos] = idx; } }
    }
  }
  __syncthreads();

  const uint32_t nA = cntA;
  if (tid < nA) { sk[tid] = av[tid]; si[tid] = ai[tid]; }

  if (w == 0) {
    const uint32_t nC = min(cntC, 2048u);
    for (uint32_t k = 0; k < need; ++k) {
      uint32_t bk = 0, bi = 0xFFFFFFFFu, bp = 0;
      for (uint32_t c = lane; c < nC; c += 64) {
        uint32_t kk = ck[c], ii = ci[c];
        if (kk > bk || (kk == bk && ii < bi)) { bk = kk; bi = ii; bp = c; }
      }
      #pragma unroll
      for (int off = 32; off >= 1; off >>= 1) {
        uint32_t ok = __shfl_down(bk, off);
        uint32_t oi = __shfl_down(bi, off);
        uint32_t op = __shfl_down(bp, off);
        if (ok > bk || (ok == bk && oi < bi)) { bk = ok; bi = oi; bp = op; }
      }
      bp = __shfl(bp, 0);
      if (lane == 0) { ck[bp] = 0; sk[nA + k] = bk; si[nA + k] = bi; }
    }
  }
  __syncthreads();

  if (tid == 0) {
    float f[KTOP]; float mx = 0.f;
    #pragma unroll
    for (int k = 0; k < KTOP; ++k) {
      uint32_t kk = sk[k];
      float fv = (kk & 0x80000000u) ? __uint_as_float(kk ^ 0x80000000u)
                                    : __uint_as_float(~kk);
      f[k] = fv; mx = fmaxf(mx, fv);
    }
    float eo = __expf(-mx);
    float Z = (float)(NKEYS - KTOP) * eo;
    float e[KTOP];
    #pragma unroll
    for (int k = 0; k < KTOP; ++k) { e[k] = __expf(f[k] - mx); Z += e[k]; }
    float inv = 1.f / Z;
    #pragma unroll
    for (int k = 0; k < KTOP; ++k) gk[k] = e[k] * inv;
    s_gother = eo * inv;
  }
  __syncthreads();

  float go = s_gother;
  float4 g4 = { go, go, go, go };
  float* grow = gates + (size_t)blockIdx.x * NKEYS;
  #pragma unroll
  for (int j = 0; j < 4; ++j) ((float4*)grow)[j * 256 + tid] = g4;
  __syncthreads();
  if (tid < KTOP) grow[si[tid]] = gk[tid];
}

extern "C" void kernel_launch(void* const* d_in, const int* in_sizes, int n_in,
                              void* d_out, int out_size, void* d_ws, size_t ws_size,
                              hipStream_t stream) {
  const float* x    = (const float*)d_in[0];
  const float* keys = (const float*)d_in[1];
  const float* W    = (const float*)d_in[2];
  const float* bias = (const float*)d_in[3];
  (void)in_sizes; (void)n_in; (void)out_size; (void)ws_size;

  float* gates  = (float*)d_out;
  float* scores = (float*)d_out + (size_t)BS_T * NKEYS;

  _Float16* W_h = (_Float16*)d_ws;                 // 4 MB
  _Float16* k_h = W_h + (size_t)KDIM * XDIM;       // 4 MB
  _Float16* q_h = k_h + (size_t)NKEYS * KDIM;      // 16 MB

  cvt_f32_f16_v<<<dim3(1024), dim3(256), 0, stream>>>(W, W_h, KDIM * XDIM / 8);
  cvt_f32_f16_v<<<dim3(1024), dim3(256), 0, stream>>>(keys, k_h, NKEYS * KDIM / 8);

  // query = x @ W^T + b -> q_h (fp16). x read ONCE; 1-barrier/K-tile pipeline
  gemm1_pipe<<<dim3(BS_T / 64), dim3(512), 0, stream>>>(x, W_h, bias, q_h);

  // scores = q @ keys^T -> fp32. 256x256 tiles, counted-vmcnt pipeline, grid 1024
  gemm2_pipe<<<dim3((BS_T / 256) * (NKEYS / 256)), dim3(512), 0, stream>>>(
      q_h, k_h, scores);

  topk_gates_kernel<<<dim3(BS_T), dim3(256), 0, stream>>>(scores, gates);
}